// Round 14
// baseline (302.902 us; speedup 1.0000x reference)
//
#include <hip/hip_runtime.h>
#include <hip/hip_bf16.h>

#define CHN 512
#define HW  4096
#define C3  1536
#define GB  4   // batches per group

typedef __hip_bfloat16 bf16;
typedef __attribute__((ext_vector_type(8))) short short8;
typedef __attribute__((ext_vector_type(4))) short short4v;
typedef __attribute__((ext_vector_type(4))) float f32x4;
typedef __attribute__((ext_vector_type(4))) int   int4v;
typedef _Float16 h8_t __attribute__((ext_vector_type(8)));

__device__ inline float b2f_bits(short s) {
    union { unsigned u; float f; } uf;
    uf.u = ((unsigned)(unsigned short)s) << 16;
    return uf.f;
}
__device__ inline short f2b_bits(float x) {
    union { __hip_bfloat16 h; short s; } u;
    u.h = __float2bfloat16(x);
    return u.s;
}
// bf16 split (x ~= hi+lo, ~2^-17): precision-critical q/k path
__device__ inline void split_bf16(float x, short& hi, short& lo) {
    hi = f2b_bits(x);
    lo = f2b_bits(x - b2f_bits(hi));
}
// f16 helpers: hi ~2^-12, hi+lo ~2^-22
__device__ inline short f2h_bits(float x) {
    _Float16 h = (_Float16)x;
    return __builtin_bit_cast(short, h);
}
__device__ inline float h2f_bits(short s) {
    return (float)__builtin_bit_cast(_Float16, s);
}
__device__ inline void split_f16(float x, short& hi, short& lo) {
    _Float16 h = (_Float16)x;
    _Float16 l = (_Float16)(x - (float)h);
    hi = __builtin_bit_cast(short, h);
    lo = __builtin_bit_cast(short, l);
}
// XOR-swizzled LDS index (short units): row-major [rows][64], 16B granules
__device__ inline int swz64(int row, int g) {
    return row * 64 + ((g ^ (row & 7)) << 3);
}
__device__ inline int swz128(int row, int g) {
    return row * 128 + ((g ^ (row & 15)) << 3);
}
// async global->LDS 16B: lane's data lands at lds_base + lane*16B
__device__ inline void gload16(const void* g, void* l) {
    __builtin_amdgcn_global_load_lds(
        (const __attribute__((address_space(1))) void*)g,
        (__attribute__((address_space(3))) void*)l, 16, 0, 0);
}

// ---------------- weights f32 -> f16 (hi only) ----------------
__global__ __launch_bounds__(256) void k_w_hi(const float* __restrict__ w,
                                              short* __restrict__ wh, int n4) {
    int i = blockIdx.x * 256 + threadIdx.x;
    if (i < n4) {
        f32x4 v = *(const f32x4*)&w[i * 4];
        short4v h;
#pragma unroll
        for (int j = 0; j < 4; ++j) h[j] = f2h_bits(v[j]);
        *(short4v*)&wh[i * 4] = h;
    }
}

// ---------------- x [C][N] f32 -> xT [N][C] f16 ----------------
__global__ __launch_bounds__(256) void k_transpose_xf16(const float* __restrict__ in,
                                                        short* __restrict__ out) {
    __shared__ float tile[64][65];
    int b = blockIdx.z;
    int c0 = blockIdx.y * 64, n0 = blockIdx.x * 64;
    const float* ip = in + (long)b * ((long)CHN * HW);
    short* op = out + (long)b * ((long)HW * CHN);
    int t = threadIdx.x;
#pragma unroll
    for (int p = 0; p < 4; ++p) {
        int id = p * 256 + t;
        int r = id >> 4, c4 = (id & 15) * 4;
        f32x4 v = *(const f32x4*)&ip[(long)(c0 + r) * HW + n0 + c4];
#pragma unroll
        for (int j = 0; j < 4; ++j) tile[r][c4 + j] = v[j];
    }
    __syncthreads();
    int col = t & 63, rr = t >> 6;
#pragma unroll
    for (int p = 0; p < 16; ++p) {
        int r = p * 4 + rr;
        op[(long)(n0 + r) * CHN + c0 + col] = f2h_bits(tile[col][r]);
    }
}

// ---------------- GEMM: C[b] = A (MxK f16 hi) * B[b]^T (NxK f16), 1-pass ----------------
// Swapped-operand MFMA (mfma(b,a)): acc reg axis = contiguous n -> vector stores.
// OUT_F16: 8B short4v stores at row stride rstride (shorts); else 16B f32x4 stores.
template <int MT, bool OUT_F16>
__global__ __launch_bounds__(256) void k_gemm_f16(const short* __restrict__ Ah,
                                                  const short* __restrict__ B,
                                                  void* __restrict__ Cv,
                                                  int M, int N, int K,
                                                  long bB, long bC, long rstride) {
    __shared__ short sAh[MT * 64], sB[128 * 64];
    int b = blockIdx.z;
    int m0 = blockIdx.y * MT, n0 = blockIdx.x * 128;
    const short* Bp = B + (long)b * bB;
    int t = threadIdx.x, wid = t >> 6, lane = t & 63;
    int wr = (wid >> 1) * (MT / 2), wc = (wid & 1) * 64;
    int lrow = lane & 15, khalf = lane >> 4;
    int lrow8 = lane >> 3;                         // 0..7 within wave's 8 rows
    int gl = ((lane & 7) ^ lrow8) << 3;            // pre-swizzled source granule (shorts)
    constexpr int MR = MT / 32;                    // acc M-fragments per wave
    f32x4 acc[MR][4] = {};
    for (int kt = 0; kt < K; kt += 64) {
#pragma unroll
        for (int i = 0; i < MT / 32; ++i) {
            int rb = i * 32 + wid * 8;
            int row = rb + lrow8;
            gload16(&Ah[(long)(m0 + row) * K + kt + gl], &sAh[rb * 64]);
        }
#pragma unroll
        for (int i = 0; i < 4; ++i) {
            int rb = i * 32 + wid * 8;
            int row = rb + lrow8;
            gload16(&Bp[(long)(n0 + row) * K + kt + gl], &sB[rb * 64]);
        }
        __syncthreads();
#pragma unroll
        for (int ks = 0; ks < 2; ++ks) {
            int gk = ks * 4 + khalf;
            h8_t ah[MR], bh[4];
#pragma unroll
            for (int i = 0; i < MR; ++i)
                ah[i] = *(const h8_t*)&sAh[swz64(wr + i * 16 + lrow, gk)];
#pragma unroll
            for (int i = 0; i < 4; ++i)
                bh[i] = *(const h8_t*)&sB[swz64(wc + i * 16 + lrow, gk)];
#pragma unroll
            for (int mi = 0; mi < MR; ++mi)
#pragma unroll
                for (int ni = 0; ni < 4; ++ni)
                    acc[mi][ni] = __builtin_amdgcn_mfma_f32_16x16x32_f16(
                        bh[ni], ah[mi], acc[mi][ni], 0, 0, 0);
        }
        __syncthreads();
    }
    // D[n][m]: n = (lane>>4)*4 + reg (contiguous), m = lane&15
    int cm = lane & 15, cn = (lane >> 4) * 4;
#pragma unroll
    for (int mi = 0; mi < MR; ++mi)
#pragma unroll
        for (int ni = 0; ni < 4; ++ni) {
            long m = m0 + wr + mi * 16 + cm;
            long n = n0 + wc + ni * 16 + cn;
            if constexpr (OUT_F16) {
                short4v v4;
#pragma unroll
                for (int r = 0; r < 4; ++r) v4[r] = f2h_bits(acc[mi][ni][r]);
                *(short4v*)&((short*)Cv)[(long)b * bC + m * rstride + n] = v4;
            } else {
                *(f32x4*)&((float*)Cv)[(long)b * bC + m * rstride + n] = acc[mi][ni];
            }
        }
}

// ---------------- fused depthwise 3x3 + (q,k) L2-norm, register column-stencil ----------------
// Input: f16 in first 8KB of each 16KB channel slot. Output in-place per slot:
// q/k channels -> [hi 4096 shorts][lo 4096 shorts]; v channels -> f16 (first half).
__global__ __launch_bounds__(256) void k_dwl2_rs(int* __restrict__ qkv,
                                                 const float* __restrict__ w) {
    __shared__ float red[4];
    int ch = blockIdx.x, b = blockIdx.y;
    bool is_qk = ch < 1024;
    int* pi = qkv + ((long)b * C3 + ch) * HW;       // slot base (HW ints = 16KB)
    short* ps = (short*)pi;
    const short* pin = (const short*)pi;            // f16 input, first 4096 shorts
    float w9[9];
#pragma unroll
    for (int i = 0; i < 9; ++i) w9[i] = w[ch * 9 + i];
    int t = threadIdx.x, wid = t >> 6, lane = t & 63;
    int y0 = wid * 16;
    float out[16];
#pragma unroll
    for (int j = 0; j < 16; ++j) out[j] = 0.f;
#pragma unroll
    for (int i = 0; i < 18; ++i) {
        int r = y0 - 1 + i;
        float v = (r >= 0 && r < 64) ? h2f_bits(pin[r * 64 + lane]) : 0.f;
        float vl = __shfl_up(v, 1);
        float vr = __shfl_down(v, 1);
        if (lane == 0) vl = 0.f;
        if (lane == 63) vr = 0.f;
        int j = i - 1;  // r - y0
        if (j + 1 >= 0 && j + 1 < 16) out[j + 1] += w9[0] * vl + w9[1] * v + w9[2] * vr;
        if (j >= 0 && j < 16)         out[j]     += w9[3] * vl + w9[4] * v + w9[5] * vr;
        if (j - 1 >= 0 && j - 1 < 16) out[j - 1] += w9[6] * vl + w9[7] * v + w9[8] * vr;
    }
    if (is_qk) {
        float ss = 0.f;
#pragma unroll
        for (int j = 0; j < 16; ++j) ss += out[j] * out[j];
#pragma unroll
        for (int o = 32; o; o >>= 1) ss += __shfl_xor(ss, o);
        if (lane == 0) red[wid] = ss;
        __syncthreads();   // also orders all loads before in-place stores
        float tot = red[0] + red[1] + red[2] + red[3];
        float sc = 1.f / fmaxf(sqrtf(tot), 1e-12f);
#pragma unroll
        for (int j = 0; j < 16; ++j) {
            short hi, lo;
            split_bf16(out[j] * sc, hi, lo);
            int n = (y0 + j) * 64 + lane;
            ps[n] = hi;
            ps[4096 + n] = lo;
        }
    } else {
        __syncthreads();   // in-place safety: all loads before any store
#pragma unroll
        for (int j = 0; j < 16; ++j)
            ps[(y0 + j) * 64 + lane] = f2h_bits(out[j]);
    }
}

// ---------------- attn partials: per (h, kslice, b): q(64xK)*k(64xK)^T, bf16 3-pass ----------------
// 16 K-slices of 256 for 2 blocks/CU; q/k staged via global_load_lds (pre-swizzled source).
__global__ __launch_bounds__(256) void k_attn_gl(const short* __restrict__ qkv_sh,
                                                 float* __restrict__ attn_part) {
    __shared__ short sQh[64 * 128], sQl[64 * 128], sKh[64 * 128], sKl[64 * 128];
    int h = blockIdx.x, ksl = blockIdx.y, b = blockIdx.z;
    // channel slot = HW*2 shorts (hi 4096 | lo 4096)
    const short* qb = qkv_sh + ((long)b * C3 + h * 64) * (HW * 2L);
    const short* kb = qb + (long)512 * HW * 2;
    int t = threadIdx.x, wid = t >> 6, lane = t & 63;
    int lrow = lane & 15, khalf = lane >> 4;
    f32x4 acc[4] = {};
    for (int kt = ksl * 256; kt < ksl * 256 + 256; kt += 128) {
#pragma unroll
        for (int i = 0; i < 4; ++i) {
            int rb = wid * 16 + i * 4;
            int row = rb + (lane >> 4);
            int gsrc = ((lane & 15) ^ (row & 15)) << 3;
            const short* qrow = qb + (long)row * (HW * 2L) + kt + gsrc;
            const short* krow = kb + (long)row * (HW * 2L) + kt + gsrc;
            gload16(qrow,        &sQh[rb * 128]);
            gload16(qrow + 4096, &sQl[rb * 128]);
            gload16(krow,        &sKh[rb * 128]);
            gload16(krow + 4096, &sKl[rb * 128]);
        }
        __syncthreads();
#pragma unroll
        for (int ks = 0; ks < 4; ++ks) {
            int gk = ks * 4 + khalf;
            short8 kh = *(const short8*)&sKh[swz128(wid * 16 + lrow, gk)];
            short8 kl = *(const short8*)&sKl[swz128(wid * 16 + lrow, gk)];
#pragma unroll
            for (int mi = 0; mi < 4; ++mi) {
                short8 qh = *(const short8*)&sQh[swz128(mi * 16 + lrow, gk)];
                short8 ql = *(const short8*)&sQl[swz128(mi * 16 + lrow, gk)];
                acc[mi] = __builtin_amdgcn_mfma_f32_16x16x32_bf16(qh, kh, acc[mi], 0, 0, 0);
                acc[mi] = __builtin_amdgcn_mfma_f32_16x16x32_bf16(ql, kh, acc[mi], 0, 0, 0);
                acc[mi] = __builtin_amdgcn_mfma_f32_16x16x32_bf16(qh, kl, acc[mi], 0, 0, 0);
            }
        }
        __syncthreads();
    }
    float* op = attn_part + (((long)b * 16 + ksl) * 8 + h) * 4096;
    int crow = (lane >> 4) * 4, ccol = lane & 15;
#pragma unroll
    for (int mi = 0; mi < 4; ++mi)
#pragma unroll
        for (int r = 0; r < 4; ++r)
            op[(mi * 16 + crow + r) * 64 + wid * 16 + ccol] = acc[mi][r];
}

// ---------------- fused 4x top-k masked softmax combine -> Wc (f32) ----------------
__global__ __launch_bounds__(256) void k_smcomb(const float* __restrict__ attn_part,
                                                const float* __restrict__ temp,
                                                const float* __restrict__ a1,
                                                const float* __restrict__ a2,
                                                const float* __restrict__ a3,
                                                const float* __restrict__ a4,
                                                float* __restrict__ Wc) {
    int t = threadIdx.x, wid = t >> 6, lane = t & 63;
    int b = blockIdx.z;
    int r = blockIdx.x * 4 + wid;   // (h, qrow) 0..511
    int h = r >> 6, qr = r & 63;
    float a = 0.f;
#pragma unroll
    for (int s = 0; s < 16; ++s)
        a += attn_part[(((long)b * 16 + s) * 8 + h) * 4096 + qr * 64 + lane];
    a *= temp[h];
    int cnt = 0;
#pragma unroll
    for (int j = 0; j < 64; ++j) {
        float aj = __shfl(a, j);
        cnt += (aj > a) ? 1 : 0;
    }
    float m = a;
#pragma unroll
    for (int o = 32; o; o >>= 1) m = fmaxf(m, __shfl_xor(m, o));
    float e = expf(a - m);
    const int kk[4] = {32, 42, 48, 51};
    float coef[4] = {a1[0], a2[0], a3[0], a4[0]};
    float out = 0.f;
#pragma unroll
    for (int i = 0; i < 4; ++i) {
        float ei = (cnt < kk[i]) ? e : 0.f;
        float d = ei;
#pragma unroll
        for (int o = 32; o; o >>= 1) d += __shfl_xor(d, o);
        out += coef[i] * ei / d;
    }
    Wc[((long)b * 8 + h) * 4096 + qr * 64 + lane] = out;
}

// ---------------- attT[n][c] = sum_d v[d][n]*Wc[c][d], f16 2-pass ----------------
// v (f16, slot first-half) transposed into LDS during staging (8-short-group XOR swizzle).
__global__ __launch_bounds__(256) void k_wv_f16(const float* __restrict__ Wc,
                                                const short* __restrict__ qkv_sh,
                                                short* __restrict__ attTs) {
    __shared__ short sVt[128 * 64];          // [n][d swizzled] f16 (16 KB)
    __shared__ short sWh[64 * 64], sWl[64 * 64];
    int nb = blockIdx.x, h = blockIdx.y, b = blockIdx.z;
    int n0 = nb * 128;
    const float* wp = Wc + ((long)b * 8 + h) * 4096;
    const short* vp = qkv_sh + ((long)b * C3 + 1024 + h * 64) * 8192L;  // slot stride 8192 sh
    int t = threadIdx.x, wid = t >> 6, lane = t & 63;
    int lrow = lane & 15, khalf = lane >> 4;
    // stage V: load v[d][n0+n8..+8] (d = lane, n8 = wave/p uniform), write transposed
#pragma unroll
    for (int p = 0; p < 4; ++p) {
        int d = lane;
        int n8 = (p * 4 + wid) * 8;
        short8 v8 = *(const short8*)&vp[(long)d * 8192 + n0 + n8];
#pragma unroll
        for (int j = 0; j < 8; ++j) {
            int n = n8 + j;
            sVt[n * 64 + (((d >> 3) ^ (n & 7)) << 3) + (d & 7)] = v8[j];
        }
    }
    // stage Wc hi/lo f16 planes
#pragma unroll
    for (int p = 0; p < 2; ++p) {
        int id = p * 256 + t, row = id >> 3, g = id & 7;
        f32x4 va = *(const f32x4*)&wp[row * 64 + g * 8];
        f32x4 vb = *(const f32x4*)&wp[row * 64 + g * 8 + 4];
        short8 hh, ll;
#pragma unroll
        for (int j = 0; j < 4; ++j) {
            short h0, l0, h1, l1;
            split_f16(va[j], h0, l0);
            split_f16(vb[j], h1, l1);
            hh[j] = h0;     ll[j] = l0;
            hh[4 + j] = h1; ll[4 + j] = l1;
        }
        int off = swz64(row, g);
        *(short8*)&sWh[off] = hh;
        *(short8*)&sWl[off] = ll;
    }
    __syncthreads();
    f32x4 acc[2][4] = {};
#pragma unroll
    for (int ks = 0; ks < 2; ++ks) {
        int gk = ks * 4 + khalf;
        h8_t vf[2], wh[4], wl[4];
#pragma unroll
        for (int i = 0; i < 2; ++i) {
            int n = wid * 32 + i * 16 + lrow;
            vf[i] = *(const h8_t*)&sVt[n * 64 + ((gk ^ (n & 7)) << 3)];
        }
#pragma unroll
        for (int i = 0; i < 4; ++i) {
            int rr = i * 16 + lrow;
            wh[i] = *(const h8_t*)&sWh[swz64(rr, gk)];
            wl[i] = *(const h8_t*)&sWl[swz64(rr, gk)];
        }
#pragma unroll
        for (int mi = 0; mi < 2; ++mi)
#pragma unroll
            for (int ni = 0; ni < 4; ++ni) {
                acc[mi][ni] = __builtin_amdgcn_mfma_f32_16x16x32_f16(
                    vf[mi], wh[ni], acc[mi][ni], 0, 0, 0);
                acc[mi][ni] = __builtin_amdgcn_mfma_f32_16x16x32_f16(
                    vf[mi], wl[ni], acc[mi][ni], 0, 0, 0);
            }
    }
    short* op = attTs + (long)b * ((long)C3 * HW * 2);
    int crow = (lane >> 4) * 4, ccol = lane & 15;
#pragma unroll
    for (int mi = 0; mi < 2; ++mi)
#pragma unroll
        for (int ni = 0; ni < 4; ++ni)
#pragma unroll
            for (int r = 0; r < 4; ++r) {
                long n = n0 + wid * 32 + mi * 16 + crow + r;
                int c = h * 64 + ni * 16 + ccol;
                op[n * CHN + c] = f2h_bits(acc[mi][ni][r]);
            }
}

extern "C" void kernel_launch(void* const* d_in, const int* in_sizes, int n_in,
                              void* d_out, int out_size, void* d_ws, size_t ws_size,
                              hipStream_t stream) {
    const float* x      = (const float*)d_in[0];
    const float* qkv_w  = (const float*)d_in[1];
    const float* dw_w   = (const float*)d_in[2];
    const float* proj_w = (const float*)d_in[3];
    const float* temp   = (const float*)d_in[4];
    const float* a1     = (const float*)d_in[5];
    const float* a2     = (const float*)d_in[6];
    const float* a3     = (const float*)d_in[7];
    const float* a4     = (const float*)d_in[8];
    float* out = (float*)d_out;

    char* ws = (char*)d_ws;
    // layout (141,033,472 B total == R1-proven cap):
    //   0           qkvi [GB][1536] x 16KB channel slots (100,663,296 B):
    //               GEMM writes f16 into first 8KB of each slot; dwl2 rewrites
    //               in-place: q/k -> [hi|lo] half-planes, v -> f16 first-half.
    //               Per-batch q-region reused as attT f16 after attn.
    //   100663296   SHARED region (33,554,432 B):
    //               xTs f16 [GB][4096][512] (16 MB, steps 1-2) then
    //               attn_part f32 [GB][16][8][4096] (8 MB, steps 4-5)
    //   138412032   Wc f32 [GB][8][64][64] (524,288 B)
    //   138936320   wph (524,288 B)
    //   139460608   wqh (1,572,864 B; ends exactly at 141,033,472)
    int*   qkvi      = (int*)(ws);
    short* xTs       = (short*)(ws + 100663296);
    float* attn_part = (float*)(ws + 100663296);
    float* Wc        = (float*)(ws + 138412032);
    short* wph       = (short*)(ws + 138936320);
    short* wqh       = (short*)(ws + 139460608);

    k_w_hi<<<256, 256, 0, stream>>>(proj_w, wph, 65536);
    k_w_hi<<<768, 256, 0, stream>>>(qkv_w, wqh, 196608);

    for (int g = 0; g < 2; ++g) {
        const float* xg = x + (long)g * GB * CHN * HW;
        float* outg = out + (long)g * GB * CHN * HW;
        // 1. x -> xTs f16 [n][c]
        k_transpose_xf16<<<dim3(64, 8, GB), 256, 0, stream>>>(xg, xTs);
        // 2. qkv = Wqkv(f16 hi) * x, 1-pass, MT=256, f16 out into slot first-half
        k_gemm_f16<256, true><<<dim3(32, 6, GB), 256, 0, stream>>>(
            wqh, xTs, qkvi, C3, HW, CHN,
            (long)HW * CHN, (long)C3 * 8192, 8192);
        // 3. depthwise 3x3 + q,k L2-norm: f16 -> hi/lo half-planes (q,k) / f16 (v)
        k_dwl2_rs<<<dim3(C3, GB), 256, 0, stream>>>(qkvi, dw_w);
        // 4. attn partials (16 K-slices, 2 blocks/CU), exact bf16 3-pass
        k_attn_gl<<<dim3(8, 16, GB), 256, 0, stream>>>((const short*)qkvi, attn_part);
        // 5. fused top-k softmax combine (16-way partial sum)
        k_smcomb<<<dim3(128, 1, GB), 256, 0, stream>>>(attn_part, temp, a1, a2, a3, a4, Wc);
        // 6. attT f16 = (Wc * v)^T, f16 2-pass, into dead q-region
        k_wv_f16<<<dim3(32, 8, GB), 256, 0, stream>>>(Wc, (const short*)qkvi, (short*)qkvi);
        // 7. out = Wproj(f16 hi) * att  (M=512, N=4096, K=512), 1-pass, f32 out
        k_gemm_f16<64, false><<<dim3(32, 8, GB), 256, 0, stream>>>(
            wph, (const short*)qkvi, outg, CHN, HW, CHN,
            (long)C3 * HW * 2, (long)CHN * HW, HW);
    }
}

// Round 15
// 273.321 us; speedup vs baseline: 1.1082x; 1.1082x over previous
//
#include <hip/hip_runtime.h>
#include <hip/hip_bf16.h>

#define CHN 512
#define HW  4096
#define C3  1536
#define GB  4   // batches per group

typedef __hip_bfloat16 bf16;
typedef __attribute__((ext_vector_type(8))) short short8;
typedef __attribute__((ext_vector_type(4))) short short4v;
typedef __attribute__((ext_vector_type(4))) float f32x4;
typedef __attribute__((ext_vector_type(4))) int   int4v;
typedef _Float16 h8_t __attribute__((ext_vector_type(8)));

__device__ inline float b2f_bits(short s) {
    union { unsigned u; float f; } uf;
    uf.u = ((unsigned)(unsigned short)s) << 16;
    return uf.f;
}
__device__ inline short f2b_bits(float x) {
    union { __hip_bfloat16 h; short s; } u;
    u.h = __float2bfloat16(x);
    return u.s;
}
// bf16 split (x ~= hi+lo, ~2^-17): precision-critical q/k path
__device__ inline void split_bf16(float x, short& hi, short& lo) {
    hi = f2b_bits(x);
    lo = f2b_bits(x - b2f_bits(hi));
}
// f16 helpers: hi ~2^-12, hi+lo ~2^-22
__device__ inline short f2h_bits(float x) {
    _Float16 h = (_Float16)x;
    return __builtin_bit_cast(short, h);
}
__device__ inline float h2f_bits(short s) {
    return (float)__builtin_bit_cast(_Float16, s);
}
__device__ inline void split_f16(float x, short& hi, short& lo) {
    _Float16 h = (_Float16)x;
    _Float16 l = (_Float16)(x - (float)h);
    hi = __builtin_bit_cast(short, h);
    lo = __builtin_bit_cast(short, l);
}
// XOR-swizzled LDS index (short units): row-major [rows][64], 16B granules
__device__ inline int swz64(int row, int g) {
    return row * 64 + ((g ^ (row & 7)) << 3);
}
__device__ inline int swz128(int row, int g) {
    return row * 128 + ((g ^ (row & 15)) << 3);
}
// async global->LDS 16B: lane's data lands at lds_base + lane*16B
__device__ inline void gload16(const void* g, void* l) {
    __builtin_amdgcn_global_load_lds(
        (const __attribute__((address_space(1))) void*)g,
        (__attribute__((address_space(3))) void*)l, 16, 0, 0);
}

// ---------------- weights f32 -> f16 (hi only) ----------------
__global__ __launch_bounds__(256) void k_w_hi(const float* __restrict__ w,
                                              short* __restrict__ wh, int n4) {
    int i = blockIdx.x * 256 + threadIdx.x;
    if (i < n4) {
        f32x4 v = *(const f32x4*)&w[i * 4];
        short4v h;
#pragma unroll
        for (int j = 0; j < 4; ++j) h[j] = f2h_bits(v[j]);
        *(short4v*)&wh[i * 4] = h;
    }
}

// ---------------- x [C][N] f32 -> xT [N][C] f16 ----------------
__global__ __launch_bounds__(256) void k_transpose_xf16(const float* __restrict__ in,
                                                        short* __restrict__ out) {
    __shared__ float tile[64][65];
    int b = blockIdx.z;
    int c0 = blockIdx.y * 64, n0 = blockIdx.x * 64;
    const float* ip = in + (long)b * ((long)CHN * HW);
    short* op = out + (long)b * ((long)HW * CHN);
    int t = threadIdx.x;
#pragma unroll
    for (int p = 0; p < 4; ++p) {
        int id = p * 256 + t;
        int r = id >> 4, c4 = (id & 15) * 4;
        f32x4 v = *(const f32x4*)&ip[(long)(c0 + r) * HW + n0 + c4];
#pragma unroll
        for (int j = 0; j < 4; ++j) tile[r][c4 + j] = v[j];
    }
    __syncthreads();
    int col = t & 63, rr = t >> 6;
#pragma unroll
    for (int p = 0; p < 16; ++p) {
        int r = p * 4 + rr;
        op[(long)(n0 + r) * CHN + c0 + col] = f2h_bits(tile[col][r]);
    }
}

// ---------------- GEMM: C[b] = A (MxK f16 hi) * B[b]^T (NxK f16), 1-pass ----------------
// Swapped-operand MFMA (mfma(b,a)): acc reg axis = contiguous n -> vector stores.
// OUT_F16: 8B short4v stores at row stride rstride (shorts); else 16B f32x4 stores.
template <int MT, bool OUT_F16>
__global__ __launch_bounds__(256) void k_gemm_f16(const short* __restrict__ Ah,
                                                  const short* __restrict__ B,
                                                  void* __restrict__ Cv,
                                                  int M, int N, int K,
                                                  long bB, long bC, long rstride) {
    __shared__ short sAh[MT * 64], sB[128 * 64];
    int b = blockIdx.z;
    int m0 = blockIdx.y * MT, n0 = blockIdx.x * 128;
    const short* Bp = B + (long)b * bB;
    int t = threadIdx.x, wid = t >> 6, lane = t & 63;
    int wr = (wid >> 1) * (MT / 2), wc = (wid & 1) * 64;
    int lrow = lane & 15, khalf = lane >> 4;
    int lrow8 = lane >> 3;                         // 0..7 within wave's 8 rows
    int gl = ((lane & 7) ^ lrow8) << 3;            // pre-swizzled source granule (shorts)
    constexpr int MR = MT / 32;                    // acc M-fragments per wave
    f32x4 acc[MR][4] = {};
    for (int kt = 0; kt < K; kt += 64) {
#pragma unroll
        for (int i = 0; i < MT / 32; ++i) {
            int rb = i * 32 + wid * 8;
            int row = rb + lrow8;
            gload16(&Ah[(long)(m0 + row) * K + kt + gl], &sAh[rb * 64]);
        }
#pragma unroll
        for (int i = 0; i < 4; ++i) {
            int rb = i * 32 + wid * 8;
            int row = rb + lrow8;
            gload16(&Bp[(long)(n0 + row) * K + kt + gl], &sB[rb * 64]);
        }
        __syncthreads();
#pragma unroll
        for (int ks = 0; ks < 2; ++ks) {
            int gk = ks * 4 + khalf;
            h8_t ah[MR], bh[4];
#pragma unroll
            for (int i = 0; i < MR; ++i)
                ah[i] = *(const h8_t*)&sAh[swz64(wr + i * 16 + lrow, gk)];
#pragma unroll
            for (int i = 0; i < 4; ++i)
                bh[i] = *(const h8_t*)&sB[swz64(wc + i * 16 + lrow, gk)];
#pragma unroll
            for (int mi = 0; mi < MR; ++mi)
#pragma unroll
                for (int ni = 0; ni < 4; ++ni)
                    acc[mi][ni] = __builtin_amdgcn_mfma_f32_16x16x32_f16(
                        bh[ni], ah[mi], acc[mi][ni], 0, 0, 0);
        }
        __syncthreads();
    }
    // D[n][m]: n = (lane>>4)*4 + reg (contiguous), m = lane&15
    int cm = lane & 15, cn = (lane >> 4) * 4;
#pragma unroll
    for (int mi = 0; mi < MR; ++mi)
#pragma unroll
        for (int ni = 0; ni < 4; ++ni) {
            long m = m0 + wr + mi * 16 + cm;
            long n = n0 + wc + ni * 16 + cn;
            if constexpr (OUT_F16) {
                short4v v4;
#pragma unroll
                for (int r = 0; r < 4; ++r) v4[r] = f2h_bits(acc[mi][ni][r]);
                *(short4v*)&((short*)Cv)[(long)b * bC + m * rstride + n] = v4;
            } else {
                *(f32x4*)&((float*)Cv)[(long)b * bC + m * rstride + n] = acc[mi][ni];
            }
        }
}

// ---------------- fused depthwise 3x3 + (q,k) L2-norm, register column-stencil ----------------
// Input: f16 in first 8KB of each 16KB channel slot. Output in-place per slot:
// q/k channels -> [hi 4096 shorts][lo 4096 shorts]; v channels -> f16 (first half).
__global__ __launch_bounds__(256) void k_dwl2_rs(int* __restrict__ qkv,
                                                 const float* __restrict__ w) {
    __shared__ float red[4];
    int ch = blockIdx.x, b = blockIdx.y;
    bool is_qk = ch < 1024;
    int* pi = qkv + ((long)b * C3 + ch) * HW;       // slot base (HW ints = 16KB)
    short* ps = (short*)pi;
    const short* pin = (const short*)pi;            // f16 input, first 4096 shorts
    float w9[9];
#pragma unroll
    for (int i = 0; i < 9; ++i) w9[i] = w[ch * 9 + i];
    int t = threadIdx.x, wid = t >> 6, lane = t & 63;
    int y0 = wid * 16;
    float out[16];
#pragma unroll
    for (int j = 0; j < 16; ++j) out[j] = 0.f;
#pragma unroll
    for (int i = 0; i < 18; ++i) {
        int r = y0 - 1 + i;
        float v = (r >= 0 && r < 64) ? h2f_bits(pin[r * 64 + lane]) : 0.f;
        float vl = __shfl_up(v, 1);
        float vr = __shfl_down(v, 1);
        if (lane == 0) vl = 0.f;
        if (lane == 63) vr = 0.f;
        int j = i - 1;  // r - y0
        if (j + 1 >= 0 && j + 1 < 16) out[j + 1] += w9[0] * vl + w9[1] * v + w9[2] * vr;
        if (j >= 0 && j < 16)         out[j]     += w9[3] * vl + w9[4] * v + w9[5] * vr;
        if (j - 1 >= 0 && j - 1 < 16) out[j - 1] += w9[6] * vl + w9[7] * v + w9[8] * vr;
    }
    if (is_qk) {
        float ss = 0.f;
#pragma unroll
        for (int j = 0; j < 16; ++j) ss += out[j] * out[j];
#pragma unroll
        for (int o = 32; o; o >>= 1) ss += __shfl_xor(ss, o);
        if (lane == 0) red[wid] = ss;
        __syncthreads();   // also orders all loads before in-place stores
        float tot = red[0] + red[1] + red[2] + red[3];
        float sc = 1.f / fmaxf(sqrtf(tot), 1e-12f);
#pragma unroll
        for (int j = 0; j < 16; ++j) {
            short hi, lo;
            split_bf16(out[j] * sc, hi, lo);
            int n = (y0 + j) * 64 + lane;
            ps[n] = hi;
            ps[4096 + n] = lo;
        }
    } else {
        __syncthreads();   // in-place safety: all loads before any store
#pragma unroll
        for (int j = 0; j < 16; ++j)
            ps[(y0 + j) * 64 + lane] = f2h_bits(out[j]);
    }
}

// ---------------- attn partials: per (h, kslice, b): q(64xK)*k(64xK)^T, bf16 3-pass ----------------
// 16 K-slices of 256 for 2 blocks/CU; q/k staged via global_load_lds (pre-swizzled source).
__global__ __launch_bounds__(256) void k_attn_gl(const short* __restrict__ qkv_sh,
                                                 float* __restrict__ attn_part) {
    __shared__ short sQh[64 * 128], sQl[64 * 128], sKh[64 * 128], sKl[64 * 128];
    int h = blockIdx.x, ksl = blockIdx.y, b = blockIdx.z;
    // channel slot = HW*2 shorts (hi 4096 | lo 4096)
    const short* qb = qkv_sh + ((long)b * C3 + h * 64) * (HW * 2L);
    const short* kb = qb + (long)512 * HW * 2;
    int t = threadIdx.x, wid = t >> 6, lane = t & 63;
    int lrow = lane & 15, khalf = lane >> 4;
    f32x4 acc[4] = {};
    for (int kt = ksl * 256; kt < ksl * 256 + 256; kt += 128) {
#pragma unroll
        for (int i = 0; i < 4; ++i) {
            int rb = wid * 16 + i * 4;
            int row = rb + (lane >> 4);
            int gsrc = ((lane & 15) ^ (row & 15)) << 3;
            const short* qrow = qb + (long)row * (HW * 2L) + kt + gsrc;
            const short* krow = kb + (long)row * (HW * 2L) + kt + gsrc;
            gload16(qrow,        &sQh[rb * 128]);
            gload16(qrow + 4096, &sQl[rb * 128]);
            gload16(krow,        &sKh[rb * 128]);
            gload16(krow + 4096, &sKl[rb * 128]);
        }
        __syncthreads();
#pragma unroll
        for (int ks = 0; ks < 4; ++ks) {
            int gk = ks * 4 + khalf;
            short8 kh = *(const short8*)&sKh[swz128(wid * 16 + lrow, gk)];
            short8 kl = *(const short8*)&sKl[swz128(wid * 16 + lrow, gk)];
#pragma unroll
            for (int mi = 0; mi < 4; ++mi) {
                short8 qh = *(const short8*)&sQh[swz128(mi * 16 + lrow, gk)];
                short8 ql = *(const short8*)&sQl[swz128(mi * 16 + lrow, gk)];
                acc[mi] = __builtin_amdgcn_mfma_f32_16x16x32_bf16(qh, kh, acc[mi], 0, 0, 0);
                acc[mi] = __builtin_amdgcn_mfma_f32_16x16x32_bf16(ql, kh, acc[mi], 0, 0, 0);
                acc[mi] = __builtin_amdgcn_mfma_f32_16x16x32_bf16(qh, kl, acc[mi], 0, 0, 0);
            }
        }
        __syncthreads();
    }
    float* op = attn_part + (((long)b * 16 + ksl) * 8 + h) * 4096;
    int crow = (lane >> 4) * 4, ccol = lane & 15;
#pragma unroll
    for (int mi = 0; mi < 4; ++mi)
#pragma unroll
        for (int r = 0; r < 4; ++r)
            op[(mi * 16 + crow + r) * 64 + wid * 16 + ccol] = acc[mi][r];
}

// ---------------- fused 4x top-k masked softmax combine -> Wc (f32) ----------------
__global__ __launch_bounds__(256) void k_smcomb(const float* __restrict__ attn_part,
                                                const float* __restrict__ temp,
                                                const float* __restrict__ a1,
                                                const float* __restrict__ a2,
                                                const float* __restrict__ a3,
                                                const float* __restrict__ a4,
                                                float* __restrict__ Wc) {
    int t = threadIdx.x, wid = t >> 6, lane = t & 63;
    int b = blockIdx.z;
    int r = blockIdx.x * 4 + wid;   // (h, qrow) 0..511
    int h = r >> 6, qr = r & 63;
    float a = 0.f;
#pragma unroll
    for (int s = 0; s < 16; ++s)
        a += attn_part[(((long)b * 16 + s) * 8 + h) * 4096 + qr * 64 + lane];
    a *= temp[h];
    int cnt = 0;
#pragma unroll
    for (int j = 0; j < 64; ++j) {
        float aj = __shfl(a, j);
        cnt += (aj > a) ? 1 : 0;
    }
    float m = a;
#pragma unroll
    for (int o = 32; o; o >>= 1) m = fmaxf(m, __shfl_xor(m, o));
    float e = expf(a - m);
    const int kk[4] = {32, 42, 48, 51};
    float coef[4] = {a1[0], a2[0], a3[0], a4[0]};
    float out = 0.f;
#pragma unroll
    for (int i = 0; i < 4; ++i) {
        float ei = (cnt < kk[i]) ? e : 0.f;
        float d = ei;
#pragma unroll
        for (int o = 32; o; o >>= 1) d += __shfl_xor(d, o);
        out += coef[i] * ei / d;
    }
    Wc[((long)b * 8 + h) * 4096 + qr * 64 + lane] = out;
}

// ---------------- attT[n][c] = sum_d v[d][n]*Wc[c][d], f16 2-pass ----------------
// v (f16, slot first-half) transposed into LDS during staging (8-short-group XOR swizzle).
__global__ __launch_bounds__(256) void k_wv_f16(const float* __restrict__ Wc,
                                                const short* __restrict__ qkv_sh,
                                                short* __restrict__ attTs) {
    __shared__ short sVt[128 * 64];          // [n][d swizzled] f16 (16 KB)
    __shared__ short sWh[64 * 64], sWl[64 * 64];
    int nb = blockIdx.x, h = blockIdx.y, b = blockIdx.z;
    int n0 = nb * 128;
    const float* wp = Wc + ((long)b * 8 + h) * 4096;
    const short* vp = qkv_sh + ((long)b * C3 + 1024 + h * 64) * 8192L;  // slot stride 8192 sh
    int t = threadIdx.x, wid = t >> 6, lane = t & 63;
    int lrow = lane & 15, khalf = lane >> 4;
    // stage V: load v[d][n0+n8..+8] (d = lane, n8 = wave/p uniform), write transposed
#pragma unroll
    for (int p = 0; p < 4; ++p) {
        int d = lane;
        int n8 = (p * 4 + wid) * 8;
        short8 v8 = *(const short8*)&vp[(long)d * 8192 + n0 + n8];
#pragma unroll
        for (int j = 0; j < 8; ++j) {
            int n = n8 + j;
            sVt[n * 64 + (((d >> 3) ^ (n & 7)) << 3) + (d & 7)] = v8[j];
        }
    }
    // stage Wc hi/lo f16 planes
#pragma unroll
    for (int p = 0; p < 2; ++p) {
        int id = p * 256 + t, row = id >> 3, g = id & 7;
        f32x4 va = *(const f32x4*)&wp[row * 64 + g * 8];
        f32x4 vb = *(const f32x4*)&wp[row * 64 + g * 8 + 4];
        short8 hh, ll;
#pragma unroll
        for (int j = 0; j < 4; ++j) {
            short h0, l0, h1, l1;
            split_f16(va[j], h0, l0);
            split_f16(vb[j], h1, l1);
            hh[j] = h0;     ll[j] = l0;
            hh[4 + j] = h1; ll[4 + j] = l1;
        }
        int off = swz64(row, g);
        *(short8*)&sWh[off] = hh;
        *(short8*)&sWl[off] = ll;
    }
    __syncthreads();
    f32x4 acc[2][4] = {};
#pragma unroll
    for (int ks = 0; ks < 2; ++ks) {
        int gk = ks * 4 + khalf;
        h8_t vf[2], wh[4], wl[4];
#pragma unroll
        for (int i = 0; i < 2; ++i) {
            int n = wid * 32 + i * 16 + lrow;
            vf[i] = *(const h8_t*)&sVt[n * 64 + ((gk ^ (n & 7)) << 3)];
        }
#pragma unroll
        for (int i = 0; i < 4; ++i) {
            int rr = i * 16 + lrow;
            wh[i] = *(const h8_t*)&sWh[swz64(rr, gk)];
            wl[i] = *(const h8_t*)&sWl[swz64(rr, gk)];
        }
#pragma unroll
        for (int mi = 0; mi < 2; ++mi)
#pragma unroll
            for (int ni = 0; ni < 4; ++ni) {
                acc[mi][ni] = __builtin_amdgcn_mfma_f32_16x16x32_f16(
                    vf[mi], wh[ni], acc[mi][ni], 0, 0, 0);
                acc[mi][ni] = __builtin_amdgcn_mfma_f32_16x16x32_f16(
                    vf[mi], wl[ni], acc[mi][ni], 0, 0, 0);
            }
    }
    short* op = attTs + (long)b * ((long)C3 * HW * 2);
    int crow = (lane >> 4) * 4, ccol = lane & 15;
#pragma unroll
    for (int mi = 0; mi < 2; ++mi)
#pragma unroll
        for (int ni = 0; ni < 4; ++ni)
#pragma unroll
            for (int r = 0; r < 4; ++r) {
                long n = n0 + wid * 32 + mi * 16 + crow + r;
                int c = h * 64 + ni * 16 + ccol;
                op[n * CHN + c] = f2h_bits(acc[mi][ni][r]);
            }
}

extern "C" void kernel_launch(void* const* d_in, const int* in_sizes, int n_in,
                              void* d_out, int out_size, void* d_ws, size_t ws_size,
                              hipStream_t stream) {
    const float* x      = (const float*)d_in[0];
    const float* qkv_w  = (const float*)d_in[1];
    const float* dw_w   = (const float*)d_in[2];
    const float* proj_w = (const float*)d_in[3];
    const float* temp   = (const float*)d_in[4];
    const float* a1     = (const float*)d_in[5];
    const float* a2     = (const float*)d_in[6];
    const float* a3     = (const float*)d_in[7];
    const float* a4     = (const float*)d_in[8];
    float* out = (float*)d_out;

    char* ws = (char*)d_ws;
    // layout (141,033,472 B total == R1-proven cap):
    //   0           qkvi [GB][1536] x 16KB channel slots (100,663,296 B):
    //               GEMM writes f16 into first 8KB of each slot; dwl2 rewrites
    //               in-place: q/k -> [hi|lo] half-planes, v -> f16 first-half.
    //               Per-batch q-region reused as attT f16 after attn.
    //   100663296   SHARED region (33,554,432 B):
    //               xTs f16 [GB][4096][512] (16 MB, steps 1-2) then
    //               attn_part f32 [GB][16][8][4096] (8 MB, steps 4-5)
    //   138412032   Wc f32 [GB][8][64][64] (524,288 B)
    //   138936320   wph (524,288 B)
    //   139460608   wqh (1,572,864 B; ends exactly at 141,033,472)
    int*   qkvi      = (int*)(ws);
    short* xTs       = (short*)(ws + 100663296);
    float* attn_part = (float*)(ws + 100663296);
    float* Wc        = (float*)(ws + 138412032);
    short* wph       = (short*)(ws + 138936320);
    short* wqh       = (short*)(ws + 139460608);

    k_w_hi<<<256, 256, 0, stream>>>(proj_w, wph, 65536);
    k_w_hi<<<768, 256, 0, stream>>>(qkv_w, wqh, 196608);

    for (int g = 0; g < 2; ++g) {
        const float* xg = x + (long)g * GB * CHN * HW;
        float* outg = out + (long)g * GB * CHN * HW;
        // 1. x -> xTs f16 [n][c]
        k_transpose_xf16<<<dim3(64, 8, GB), 256, 0, stream>>>(xg, xTs);
        // 2. qkv = Wqkv(f16 hi) * x, 1-pass, MT=128, f16 out into slot first-half
        k_gemm_f16<128, true><<<dim3(32, 12, GB), 256, 0, stream>>>(
            wqh, xTs, qkvi, C3, HW, CHN,
            (long)HW * CHN, (long)C3 * 8192, 8192);
        // 3. depthwise 3x3 + q,k L2-norm: f16 -> hi/lo half-planes (q,k) / f16 (v)
        k_dwl2_rs<<<dim3(C3, GB), 256, 0, stream>>>(qkvi, dw_w);
        // 4. attn partials (16 K-slices, 2 blocks/CU), exact bf16 3-pass
        k_attn_gl<<<dim3(8, 16, GB), 256, 0, stream>>>((const short*)qkvi, attn_part);
        // 5. fused top-k softmax combine (16-way partial sum)
        k_smcomb<<<dim3(128, 1, GB), 256, 0, stream>>>(attn_part, temp, a1, a2, a3, a4, Wc);
        // 6. attT f16 = (Wc * v)^T, f16 2-pass, into dead q-region
        k_wv_f16<<<dim3(32, 8, GB), 256, 0, stream>>>(Wc, (const short*)qkvi, (short*)qkvi);
        // 7. out = Wproj(f16 hi) * att  (M=512, N=4096, K=512), 1-pass, f32 out
        k_gemm_f16<64, false><<<dim3(32, 8, GB), 256, 0, stream>>>(
            wph, (const short*)qkvi, outg, CHN, HW, CHN,
            (long)C3 * HW * 2, (long)CHN * HW, HW);
    }
}

// Round 16
// 247.494 us; speedup vs baseline: 1.2239x; 1.1044x over previous
//
#include <hip/hip_runtime.h>
#include <hip/hip_bf16.h>

#define CHN 512
#define HW  4096
#define C3  1536
#define GB  4   // batches per group

typedef __hip_bfloat16 bf16;
typedef __attribute__((ext_vector_type(8))) short short8;
typedef __attribute__((ext_vector_type(4))) short short4v;
typedef __attribute__((ext_vector_type(4))) float f32x4;
typedef __attribute__((ext_vector_type(4))) int   int4v;
typedef _Float16 h8_t __attribute__((ext_vector_type(8)));

// f16 helpers: hi ~2^-12, hi+lo ~2^-22
__device__ inline short f2h_bits(float x) {
    _Float16 h = (_Float16)x;
    return __builtin_bit_cast(short, h);
}
__device__ inline float h2f_bits(short s) {
    return (float)__builtin_bit_cast(_Float16, s);
}
__device__ inline void split_f16(float x, short& hi, short& lo) {
    _Float16 h = (_Float16)x;
    _Float16 l = (_Float16)(x - (float)h);
    hi = __builtin_bit_cast(short, h);
    lo = __builtin_bit_cast(short, l);
}
// XOR-swizzled LDS index (short units): row-major [rows][64], 16B granules
__device__ inline int swz64(int row, int g) {
    return row * 64 + ((g ^ (row & 7)) << 3);
}
__device__ inline int swz128(int row, int g) {
    return row * 128 + ((g ^ (row & 15)) << 3);
}
// async global->LDS 16B: lane's data lands at lds_base + lane*16B
__device__ inline void gload16(const void* g, void* l) {
    __builtin_amdgcn_global_load_lds(
        (const __attribute__((address_space(1))) void*)g,
        (__attribute__((address_space(3))) void*)l, 16, 0, 0);
}

// ---------------- both weight tensors f32 -> f16 (hi), one launch ----------------
__global__ __launch_bounds__(256) void k_w_hi2(const float* __restrict__ wp_,
                                               short* __restrict__ wph,
                                               const float* __restrict__ wq_,
                                               short* __restrict__ wqh) {
    int i = blockIdx.x * 256 + threadIdx.x;
    const float* src;
    short* dst;
    int j;
    if (i < 65536) { src = wp_; dst = wph; j = i; }
    else           { src = wq_; dst = wqh; j = i - 65536; }
    f32x4 v = *(const f32x4*)&src[j * 4];
    short4v h;
#pragma unroll
    for (int k = 0; k < 4; ++k) h[k] = f2h_bits(v[k]);
    *(short4v*)&dst[j * 4] = h;
}

// ---------------- x [C][N] f32 -> xT [N][C] f16 ----------------
__global__ __launch_bounds__(256) void k_transpose_xf16(const float* __restrict__ in,
                                                        short* __restrict__ out) {
    __shared__ float tile[64][65];
    int b = blockIdx.z;
    int c0 = blockIdx.y * 64, n0 = blockIdx.x * 64;
    const float* ip = in + (long)b * ((long)CHN * HW);
    short* op = out + (long)b * ((long)HW * CHN);
    int t = threadIdx.x;
#pragma unroll
    for (int p = 0; p < 4; ++p) {
        int id = p * 256 + t;
        int r = id >> 4, c4 = (id & 15) * 4;
        f32x4 v = *(const f32x4*)&ip[(long)(c0 + r) * HW + n0 + c4];
#pragma unroll
        for (int j = 0; j < 4; ++j) tile[r][c4 + j] = v[j];
    }
    __syncthreads();
    int col = t & 63, rr = t >> 6;
#pragma unroll
    for (int p = 0; p < 16; ++p) {
        int r = p * 4 + rr;
        op[(long)(n0 + r) * CHN + c0 + col] = f2h_bits(tile[col][r]);
    }
}

// ---------------- GEMM: C[b] = A (MxK f16 hi) * B[b]^T (NxK f16), 1-pass ----------------
// (R13-proven geometry: MT=128, direct scalar stores)
template <int MT, bool OUT_F16>
__global__ __launch_bounds__(256) void k_gemm_f16(const short* __restrict__ Ah,
                                                  const short* __restrict__ B,
                                                  void* __restrict__ Cv,
                                                  int M, int N, int K,
                                                  long bB, long bC, long rstride) {
    __shared__ short sAh[MT * 64], sB[128 * 64];
    int b = blockIdx.z;
    int m0 = blockIdx.y * MT, n0 = blockIdx.x * 128;
    const short* Bp = B + (long)b * bB;
    int t = threadIdx.x, wid = t >> 6, lane = t & 63;
    int wr = (wid >> 1) * (MT / 2), wc = (wid & 1) * 64;
    int lrow = lane & 15, khalf = lane >> 4;
    int lrow8 = lane >> 3;                         // 0..7 within wave's 8 rows
    int gl = ((lane & 7) ^ lrow8) << 3;            // pre-swizzled source granule (shorts)
    constexpr int MR = MT / 32;                    // acc M-fragments per wave
    f32x4 acc[MR][4] = {};
    for (int kt = 0; kt < K; kt += 64) {
#pragma unroll
        for (int i = 0; i < MT / 32; ++i) {
            int rb = i * 32 + wid * 8;
            int row = rb + lrow8;
            gload16(&Ah[(long)(m0 + row) * K + kt + gl], &sAh[rb * 64]);
        }
#pragma unroll
        for (int i = 0; i < 4; ++i) {
            int rb = i * 32 + wid * 8;
            int row = rb + lrow8;
            gload16(&Bp[(long)(n0 + row) * K + kt + gl], &sB[rb * 64]);
        }
        __syncthreads();
#pragma unroll
        for (int ks = 0; ks < 2; ++ks) {
            int gk = ks * 4 + khalf;
            h8_t ah[MR], bh[4];
#pragma unroll
            for (int i = 0; i < MR; ++i)
                ah[i] = *(const h8_t*)&sAh[swz64(wr + i * 16 + lrow, gk)];
#pragma unroll
            for (int i = 0; i < 4; ++i)
                bh[i] = *(const h8_t*)&sB[swz64(wc + i * 16 + lrow, gk)];
#pragma unroll
            for (int mi = 0; mi < MR; ++mi)
#pragma unroll
                for (int ni = 0; ni < 4; ++ni)
                    acc[mi][ni] = __builtin_amdgcn_mfma_f32_16x16x32_f16(
                        ah[mi], bh[ni], acc[mi][ni], 0, 0, 0);
        }
        __syncthreads();
    }
    int crow = (lane >> 4) * 4, ccol = lane & 15;
#pragma unroll
    for (int mi = 0; mi < MR; ++mi)
#pragma unroll
        for (int ni = 0; ni < 4; ++ni)
#pragma unroll
            for (int r = 0; r < 4; ++r) {
                long row = m0 + wr + mi * 16 + crow + r;
                long col = n0 + wc + ni * 16 + ccol;
                float v = acc[mi][ni][r];
                if constexpr (OUT_F16)
                    ((short*)Cv)[(long)b * bC + row * rstride + col] = f2h_bits(v);
                else
                    ((float*)Cv)[(long)b * bC + row * rstride + col] = v;
            }
}

// ---------------- fused depthwise 3x3 + (q,k) L2-norm, register column-stencil ----------------
// Input: f16 in first 8KB of each 16KB channel slot. Output in-place: f16 first-half,
// q/k channels (ch<1024) scaled by 1/||.||.
__global__ __launch_bounds__(256) void k_dwl2_rs(short* __restrict__ qkv,
                                                 const float* __restrict__ w) {
    __shared__ float red[4];
    int ch = blockIdx.x, b = blockIdx.y;
    bool is_qk = ch < 1024;
    short* ps = qkv + ((long)b * C3 + ch) * 8192L;  // slot base (8192 shorts = 16KB)
    float w9[9];
#pragma unroll
    for (int i = 0; i < 9; ++i) w9[i] = w[ch * 9 + i];
    int t = threadIdx.x, wid = t >> 6, lane = t & 63;
    int y0 = wid * 16;
    float out[16];
#pragma unroll
    for (int j = 0; j < 16; ++j) out[j] = 0.f;
#pragma unroll
    for (int i = 0; i < 18; ++i) {
        int r = y0 - 1 + i;
        float v = (r >= 0 && r < 64) ? h2f_bits(ps[r * 64 + lane]) : 0.f;
        float vl = __shfl_up(v, 1);
        float vr = __shfl_down(v, 1);
        if (lane == 0) vl = 0.f;
        if (lane == 63) vr = 0.f;
        int j = i - 1;  // r - y0
        if (j + 1 >= 0 && j + 1 < 16) out[j + 1] += w9[0] * vl + w9[1] * v + w9[2] * vr;
        if (j >= 0 && j < 16)         out[j]     += w9[3] * vl + w9[4] * v + w9[5] * vr;
        if (j - 1 >= 0 && j - 1 < 16) out[j - 1] += w9[6] * vl + w9[7] * v + w9[8] * vr;
    }
    float sc = 1.f;
    if (is_qk) {
        float ss = 0.f;
#pragma unroll
        for (int j = 0; j < 16; ++j) ss += out[j] * out[j];
#pragma unroll
        for (int o = 32; o; o >>= 1) ss += __shfl_xor(ss, o);
        if (lane == 0) red[wid] = ss;
        __syncthreads();   // orders all loads before in-place stores
        float tot = red[0] + red[1] + red[2] + red[3];
        sc = 1.f / fmaxf(sqrtf(tot), 1e-12f);
    } else {
        __syncthreads();   // in-place safety: all loads before any store
    }
#pragma unroll
    for (int j = 0; j < 16; ++j)
        ps[(y0 + j) * 64 + lane] = f2h_bits(out[j] * sc);
}

// ---------------- attn partials: per (h, kslice, b): q(64xK)*k(64xK)^T, 1-pass f16 ----------------
// 16 K-slices of 256; q/k staged via global_load_lds (pre-swizzled source).
__global__ __launch_bounds__(256) void k_attn_gl(const short* __restrict__ qkv_sh,
                                                 float* __restrict__ attn_part) {
    __shared__ short sQ[64 * 128], sK[64 * 128];
    int h = blockIdx.x, ksl = blockIdx.y, b = blockIdx.z;
    const short* qb = qkv_sh + ((long)b * C3 + h * 64) * 8192L;   // f16 plane, slot stride
    const short* kb = qb + (long)512 * 8192;
    int t = threadIdx.x, wid = t >> 6, lane = t & 63;
    int lrow = lane & 15, khalf = lane >> 4;
    f32x4 acc[4] = {};
    for (int kt = ksl * 256; kt < ksl * 256 + 256; kt += 128) {
#pragma unroll
        for (int i = 0; i < 4; ++i) {
            int rb = wid * 16 + i * 4;
            int row = rb + (lane >> 4);
            int gsrc = ((lane & 15) ^ (row & 15)) << 3;
            gload16(qb + (long)row * 8192 + kt + gsrc, &sQ[rb * 128]);
            gload16(kb + (long)row * 8192 + kt + gsrc, &sK[rb * 128]);
        }
        __syncthreads();
#pragma unroll
        for (int ks = 0; ks < 4; ++ks) {
            int gk = ks * 4 + khalf;
            h8_t kf = *(const h8_t*)&sK[swz128(wid * 16 + lrow, gk)];
#pragma unroll
            for (int mi = 0; mi < 4; ++mi) {
                h8_t qf = *(const h8_t*)&sQ[swz128(mi * 16 + lrow, gk)];
                acc[mi] = __builtin_amdgcn_mfma_f32_16x16x32_f16(qf, kf, acc[mi], 0, 0, 0);
            }
        }
        __syncthreads();
    }
    float* op = attn_part + (((long)b * 16 + ksl) * 8 + h) * 4096;
    int crow = (lane >> 4) * 4, ccol = lane & 15;
#pragma unroll
    for (int mi = 0; mi < 4; ++mi)
#pragma unroll
        for (int r = 0; r < 4; ++r)
            op[(mi * 16 + crow + r) * 64 + wid * 16 + ccol] = acc[mi][r];
}

// ---------------- fused 4x top-k masked softmax combine -> Wc (f32) ----------------
__global__ __launch_bounds__(256) void k_smcomb(const float* __restrict__ attn_part,
                                                const float* __restrict__ temp,
                                                const float* __restrict__ a1,
                                                const float* __restrict__ a2,
                                                const float* __restrict__ a3,
                                                const float* __restrict__ a4,
                                                float* __restrict__ Wc) {
    int t = threadIdx.x, wid = t >> 6, lane = t & 63;
    int b = blockIdx.z;
    int r = blockIdx.x * 4 + wid;   // (h, qrow) 0..511
    int h = r >> 6, qr = r & 63;
    float a = 0.f;
#pragma unroll
    for (int s = 0; s < 16; ++s)
        a += attn_part[(((long)b * 16 + s) * 8 + h) * 4096 + qr * 64 + lane];
    a *= temp[h];
    int cnt = 0;
#pragma unroll
    for (int j = 0; j < 64; ++j) {
        float aj = __shfl(a, j);
        cnt += (aj > a) ? 1 : 0;
    }
    float m = a;
#pragma unroll
    for (int o = 32; o; o >>= 1) m = fmaxf(m, __shfl_xor(m, o));
    float e = expf(a - m);
    const int kk[4] = {32, 42, 48, 51};
    float coef[4] = {a1[0], a2[0], a3[0], a4[0]};
    float out = 0.f;
#pragma unroll
    for (int i = 0; i < 4; ++i) {
        float ei = (cnt < kk[i]) ? e : 0.f;
        float d = ei;
#pragma unroll
        for (int o = 32; o; o >>= 1) d += __shfl_xor(d, o);
        out += coef[i] * ei / d;
    }
    Wc[((long)b * 8 + h) * 4096 + qr * 64 + lane] = out;
}

// ---------------- attT[n][c] = sum_d v[d][n]*Wc[c][d], f16 2-pass ----------------
// v (f16, slot first-half) transposed into LDS during staging (8-short-group XOR swizzle).
__global__ __launch_bounds__(256) void k_wv_f16(const float* __restrict__ Wc,
                                                const short* __restrict__ qkv_sh,
                                                short* __restrict__ attTs) {
    __shared__ short sVt[128 * 64];          // [n][d swizzled] f16 (16 KB)
    __shared__ short sWh[64 * 64], sWl[64 * 64];
    int nb = blockIdx.x, h = blockIdx.y, b = blockIdx.z;
    int n0 = nb * 128;
    const float* wp = Wc + ((long)b * 8 + h) * 4096;
    const short* vp = qkv_sh + ((long)b * C3 + 1024 + h * 64) * 8192L;  // slot stride 8192 sh
    int t = threadIdx.x, wid = t >> 6, lane = t & 63;
    int lrow = lane & 15, khalf = lane >> 4;
    // stage V: load v[d][n0+n8..+8] (d = lane, n8 = wave/p uniform), write transposed
#pragma unroll
    for (int p = 0; p < 4; ++p) {
        int d = lane;
        int n8 = (p * 4 + wid) * 8;
        short8 v8 = *(const short8*)&vp[(long)d * 8192 + n0 + n8];
#pragma unroll
        for (int j = 0; j < 8; ++j) {
            int n = n8 + j;
            sVt[n * 64 + (((d >> 3) ^ (n & 7)) << 3) + (d & 7)] = v8[j];
        }
    }
    // stage Wc hi/lo f16 planes
#pragma unroll
    for (int p = 0; p < 2; ++p) {
        int id = p * 256 + t, row = id >> 3, g = id & 7;
        f32x4 va = *(const f32x4*)&wp[row * 64 + g * 8];
        f32x4 vb = *(const f32x4*)&wp[row * 64 + g * 8 + 4];
        short8 hh, ll;
#pragma unroll
        for (int j = 0; j < 4; ++j) {
            short h0, l0, h1, l1;
            split_f16(va[j], h0, l0);
            split_f16(vb[j], h1, l1);
            hh[j] = h0;     ll[j] = l0;
            hh[4 + j] = h1; ll[4 + j] = l1;
        }
        int off = swz64(row, g);
        *(short8*)&sWh[off] = hh;
        *(short8*)&sWl[off] = ll;
    }
    __syncthreads();
    f32x4 acc[2][4] = {};
#pragma unroll
    for (int ks = 0; ks < 2; ++ks) {
        int gk = ks * 4 + khalf;
        h8_t vf[2], wh[4], wl[4];
#pragma unroll
        for (int i = 0; i < 2; ++i) {
            int n = wid * 32 + i * 16 + lrow;
            vf[i] = *(const h8_t*)&sVt[n * 64 + ((gk ^ (n & 7)) << 3)];
        }
#pragma unroll
        for (int i = 0; i < 4; ++i) {
            int rr = i * 16 + lrow;
            wh[i] = *(const h8_t*)&sWh[swz64(rr, gk)];
            wl[i] = *(const h8_t*)&sWl[swz64(rr, gk)];
        }
#pragma unroll
        for (int mi = 0; mi < 2; ++mi)
#pragma unroll
            for (int ni = 0; ni < 4; ++ni) {
                acc[mi][ni] = __builtin_amdgcn_mfma_f32_16x16x32_f16(
                    vf[mi], wh[ni], acc[mi][ni], 0, 0, 0);
                acc[mi][ni] = __builtin_amdgcn_mfma_f32_16x16x32_f16(
                    vf[mi], wl[ni], acc[mi][ni], 0, 0, 0);
            }
    }
    short* op = attTs + (long)b * ((long)C3 * HW * 2);
    int crow = (lane >> 4) * 4, ccol = lane & 15;
#pragma unroll
    for (int mi = 0; mi < 2; ++mi)
#pragma unroll
        for (int ni = 0; ni < 4; ++ni)
#pragma unroll
            for (int r = 0; r < 4; ++r) {
                long n = n0 + wid * 32 + mi * 16 + crow + r;
                int c = h * 64 + ni * 16 + ccol;
                op[n * CHN + c] = f2h_bits(acc[mi][ni][r]);
            }
}

extern "C" void kernel_launch(void* const* d_in, const int* in_sizes, int n_in,
                              void* d_out, int out_size, void* d_ws, size_t ws_size,
                              hipStream_t stream) {
    const float* x      = (const float*)d_in[0];
    const float* qkv_w  = (const float*)d_in[1];
    const float* dw_w   = (const float*)d_in[2];
    const float* proj_w = (const float*)d_in[3];
    const float* temp   = (const float*)d_in[4];
    const float* a1     = (const float*)d_in[5];
    const float* a2     = (const float*)d_in[6];
    const float* a3     = (const float*)d_in[7];
    const float* a4     = (const float*)d_in[8];
    float* out = (float*)d_out;

    char* ws = (char*)d_ws;
    // layout (141,033,472 B total == R1-proven cap):
    //   0           qkvi [GB][1536] x 16KB channel slots (100,663,296 B):
    //               GEMM writes f16 into first 8KB of each slot; dwl2 rewrites
    //               in-place (f16, q/k l2-scaled). Per-batch q-region reused as
    //               attT f16 after attn.
    //   100663296   SHARED region (33,554,432 B):
    //               xTs f16 [GB][4096][512] (16 MB, steps 1-2) then
    //               attn_part f32 [GB][16][8][4096] (8 MB, steps 4-5)
    //   138412032   Wc f32 [GB][8][64][64] (524,288 B)
    //   138936320   wph (524,288 B)
    //   139460608   wqh (1,572,864 B; ends exactly at 141,033,472)
    short* qkvi      = (short*)(ws);
    short* xTs       = (short*)(ws + 100663296);
    float* attn_part = (float*)(ws + 100663296);
    float* Wc        = (float*)(ws + 138412032);
    short* wph       = (short*)(ws + 138936320);
    short* wqh       = (short*)(ws + 139460608);

    k_w_hi2<<<1024, 256, 0, stream>>>(proj_w, wph, qkv_w, wqh);

    for (int g = 0; g < 2; ++g) {
        const float* xg = x + (long)g * GB * CHN * HW;
        float* outg = out + (long)g * GB * CHN * HW;
        // 1. x -> xTs f16 [n][c]
        k_transpose_xf16<<<dim3(64, 8, GB), 256, 0, stream>>>(xg, xTs);
        // 2. qkv = Wqkv(f16 hi) * x, 1-pass, MT=128, f16 out into slot first-half
        k_gemm_f16<128, true><<<dim3(32, 12, GB), 256, 0, stream>>>(
            wqh, xTs, qkvi, C3, HW, CHN,
            (long)HW * CHN, (long)C3 * 8192, 8192);
        // 3. depthwise 3x3 + q,k L2-norm: f16 in-place
        k_dwl2_rs<<<dim3(C3, GB), 256, 0, stream>>>(qkvi, dw_w);
        // 4. attn partials (16 K-slices), 1-pass f16
        k_attn_gl<<<dim3(8, 16, GB), 256, 0, stream>>>(qkvi, attn_part);
        // 5. fused top-k softmax combine (16-way partial sum)
        k_smcomb<<<dim3(128, 1, GB), 256, 0, stream>>>(attn_part, temp, a1, a2, a3, a4, Wc);
        // 6. attT f16 = (Wc * v)^T, f16 2-pass, into dead q-region
        k_wv_f16<<<dim3(32, 8, GB), 256, 0, stream>>>(Wc, qkvi, qkvi);
        // 7. out = Wproj(f16 hi) * att  (M=512, N=4096, K=512), 1-pass, f32 out
        k_gemm_f16<64, false><<<dim3(32, 8, GB), 256, 0, stream>>>(
            wph, qkvi, outg, CHN, HW, CHN,
            (long)C3 * HW * 2, (long)CHN * HW, HW);
    }
}

// Round 17
// 231.127 us; speedup vs baseline: 1.3105x; 1.0708x over previous
//
#include <hip/hip_runtime.h>
#include <hip/hip_bf16.h>

#define CHN 512
#define HW  4096
#define C3  1536

typedef __hip_bfloat16 bf16;
typedef __attribute__((ext_vector_type(8))) short short8;
typedef __attribute__((ext_vector_type(4))) short short4v;
typedef __attribute__((ext_vector_type(4))) float f32x4;
typedef __attribute__((ext_vector_type(4))) int   int4v;
typedef _Float16 h8_t __attribute__((ext_vector_type(8)));

// f16 helpers: hi ~2^-12, hi+lo ~2^-22
__device__ inline short f2h_bits(float x) {
    _Float16 h = (_Float16)x;
    return __builtin_bit_cast(short, h);
}
__device__ inline float h2f_bits(short s) {
    return (float)__builtin_bit_cast(_Float16, s);
}
__device__ inline void split_f16(float x, short& hi, short& lo) {
    _Float16 h = (_Float16)x;
    _Float16 l = (_Float16)(x - (float)h);
    hi = __builtin_bit_cast(short, h);
    lo = __builtin_bit_cast(short, l);
}
// XOR-swizzled LDS index (short units): row-major [rows][64], 16B granules
__device__ inline int swz64(int row, int g) {
    return row * 64 + ((g ^ (row & 7)) << 3);
}
__device__ inline int swz128(int row, int g) {
    return row * 128 + ((g ^ (row & 15)) << 3);
}
// async global->LDS 16B: lane's data lands at lds_base + lane*16B
__device__ inline void gload16(const void* g, void* l) {
    __builtin_amdgcn_global_load_lds(
        (const __attribute__((address_space(1))) void*)g,
        (__attribute__((address_space(3))) void*)l, 16, 0, 0);
}

// ---------------- both weight tensors f32 -> f16 (hi), one launch ----------------
__global__ __launch_bounds__(256) void k_w_hi2(const float* __restrict__ wp_,
                                               short* __restrict__ wph,
                                               const float* __restrict__ wq_,
                                               short* __restrict__ wqh) {
    int i = blockIdx.x * 256 + threadIdx.x;
    const float* src;
    short* dst;
    int j;
    if (i < 65536) { src = wp_; dst = wph; j = i; }
    else           { src = wq_; dst = wqh; j = i - 65536; }
    f32x4 v = *(const f32x4*)&src[j * 4];
    short4v h;
#pragma unroll
    for (int k = 0; k < 4; ++k) h[k] = f2h_bits(v[k]);
    *(short4v*)&dst[j * 4] = h;
}

// ---------------- x [C][N] f32 -> xT [N][C] f16 ----------------
__global__ __launch_bounds__(256) void k_transpose_xf16(const float* __restrict__ in,
                                                        short* __restrict__ out) {
    __shared__ float tile[64][65];
    int b = blockIdx.z;
    int c0 = blockIdx.y * 64, n0 = blockIdx.x * 64;
    const float* ip = in + (long)b * ((long)CHN * HW);
    short* op = out + (long)b * ((long)HW * CHN);
    int t = threadIdx.x;
#pragma unroll
    for (int p = 0; p < 4; ++p) {
        int id = p * 256 + t;
        int r = id >> 4, c4 = (id & 15) * 4;
        f32x4 v = *(const f32x4*)&ip[(long)(c0 + r) * HW + n0 + c4];
#pragma unroll
        for (int j = 0; j < 4; ++j) tile[r][c4 + j] = v[j];
    }
    __syncthreads();
    int col = t & 63, rr = t >> 6;
#pragma unroll
    for (int p = 0; p < 16; ++p) {
        int r = p * 4 + rr;
        op[(long)(n0 + r) * CHN + c0 + col] = f2h_bits(tile[col][r]);
    }
}

// ---------------- GEMM: C[b] = A (MxK f16 hi) * B[b]^T (NxK f16), 1-pass ----------------
// (R13-proven geometry: MT=128, direct scalar stores)
template <int MT, bool OUT_F16>
__global__ __launch_bounds__(256) void k_gemm_f16(const short* __restrict__ Ah,
                                                  const short* __restrict__ B,
                                                  void* __restrict__ Cv,
                                                  int M, int N, int K,
                                                  long bB, long bC, long rstride) {
    __shared__ short sAh[MT * 64], sB[128 * 64];
    int b = blockIdx.z;
    int m0 = blockIdx.y * MT, n0 = blockIdx.x * 128;
    const short* Bp = B + (long)b * bB;
    int t = threadIdx.x, wid = t >> 6, lane = t & 63;
    int wr = (wid >> 1) * (MT / 2), wc = (wid & 1) * 64;
    int lrow = lane & 15, khalf = lane >> 4;
    int lrow8 = lane >> 3;                         // 0..7 within wave's 8 rows
    int gl = ((lane & 7) ^ lrow8) << 3;            // pre-swizzled source granule (shorts)
    constexpr int MR = MT / 32;                    // acc M-fragments per wave
    f32x4 acc[MR][4] = {};
    for (int kt = 0; kt < K; kt += 64) {
#pragma unroll
        for (int i = 0; i < MT / 32; ++i) {
            int rb = i * 32 + wid * 8;
            int row = rb + lrow8;
            gload16(&Ah[(long)(m0 + row) * K + kt + gl], &sAh[rb * 64]);
        }
#pragma unroll
        for (int i = 0; i < 4; ++i) {
            int rb = i * 32 + wid * 8;
            int row = rb + lrow8;
            gload16(&Bp[(long)(n0 + row) * K + kt + gl], &sB[rb * 64]);
        }
        __syncthreads();
#pragma unroll
        for (int ks = 0; ks < 2; ++ks) {
            int gk = ks * 4 + khalf;
            h8_t ah[MR], bh[4];
#pragma unroll
            for (int i = 0; i < MR; ++i)
                ah[i] = *(const h8_t*)&sAh[swz64(wr + i * 16 + lrow, gk)];
#pragma unroll
            for (int i = 0; i < 4; ++i)
                bh[i] = *(const h8_t*)&sB[swz64(wc + i * 16 + lrow, gk)];
#pragma unroll
            for (int mi = 0; mi < MR; ++mi)
#pragma unroll
                for (int ni = 0; ni < 4; ++ni)
                    acc[mi][ni] = __builtin_amdgcn_mfma_f32_16x16x32_f16(
                        ah[mi], bh[ni], acc[mi][ni], 0, 0, 0);
        }
        __syncthreads();
    }
    int crow = (lane >> 4) * 4, ccol = lane & 15;
#pragma unroll
    for (int mi = 0; mi < MR; ++mi)
#pragma unroll
        for (int ni = 0; ni < 4; ++ni)
#pragma unroll
            for (int r = 0; r < 4; ++r) {
                long row = m0 + wr + mi * 16 + crow + r;
                long col = n0 + wc + ni * 16 + ccol;
                float v = acc[mi][ni][r];
                if constexpr (OUT_F16)
                    ((short*)Cv)[(long)b * bC + row * rstride + col] = f2h_bits(v);
                else
                    ((float*)Cv)[(long)b * bC + row * rstride + col] = v;
            }
}

// ---------------- fused depthwise 3x3 + (q,k) L2-norm, register column-stencil ----------------
// Input: f16 in first 8KB of each 16KB channel slot. Output in-place: f16 first-half,
// q/k channels (ch<1024) scaled by 1/||.||.
__global__ __launch_bounds__(256) void k_dwl2_rs(short* __restrict__ qkv,
                                                 const float* __restrict__ w) {
    __shared__ float red[4];
    int ch = blockIdx.x, b = blockIdx.y;
    bool is_qk = ch < 1024;
    short* ps = qkv + ((long)b * C3 + ch) * 8192L;  // slot base (8192 shorts = 16KB)
    float w9[9];
#pragma unroll
    for (int i = 0; i < 9; ++i) w9[i] = w[ch * 9 + i];
    int t = threadIdx.x, wid = t >> 6, lane = t & 63;
    int y0 = wid * 16;
    float out[16];
#pragma unroll
    for (int j = 0; j < 16; ++j) out[j] = 0.f;
#pragma unroll
    for (int i = 0; i < 18; ++i) {
        int r = y0 - 1 + i;
        float v = (r >= 0 && r < 64) ? h2f_bits(ps[r * 64 + lane]) : 0.f;
        float vl = __shfl_up(v, 1);
        float vr = __shfl_down(v, 1);
        if (lane == 0) vl = 0.f;
        if (lane == 63) vr = 0.f;
        int j = i - 1;  // r - y0
        if (j + 1 >= 0 && j + 1 < 16) out[j + 1] += w9[0] * vl + w9[1] * v + w9[2] * vr;
        if (j >= 0 && j < 16)         out[j]     += w9[3] * vl + w9[4] * v + w9[5] * vr;
        if (j - 1 >= 0 && j - 1 < 16) out[j - 1] += w9[6] * vl + w9[7] * v + w9[8] * vr;
    }
    float sc = 1.f;
    if (is_qk) {
        float ss = 0.f;
#pragma unroll
        for (int j = 0; j < 16; ++j) ss += out[j] * out[j];
#pragma unroll
        for (int o = 32; o; o >>= 1) ss += __shfl_xor(ss, o);
        if (lane == 0) red[wid] = ss;
        __syncthreads();   // orders all loads before in-place stores
        float tot = red[0] + red[1] + red[2] + red[3];
        sc = 1.f / fmaxf(sqrtf(tot), 1e-12f);
    } else {
        __syncthreads();   // in-place safety: all loads before any store
    }
#pragma unroll
    for (int j = 0; j < 16; ++j)
        ps[(y0 + j) * 64 + lane] = f2h_bits(out[j] * sc);
}

// ---------------- attn partials: per (h, kslice, b): q(64xK)*k(64xK)^T, 1-pass f16 ----------------
// 16 K-slices of 256; q/k staged via global_load_lds (pre-swizzled source).
__global__ __launch_bounds__(256) void k_attn_gl(const short* __restrict__ qkv_sh,
                                                 float* __restrict__ attn_part) {
    __shared__ short sQ[64 * 128], sK[64 * 128];
    int h = blockIdx.x, ksl = blockIdx.y, b = blockIdx.z;
    const short* qb = qkv_sh + ((long)b * C3 + h * 64) * 8192L;   // f16 plane, slot stride
    const short* kb = qb + (long)512 * 8192;
    int t = threadIdx.x, wid = t >> 6, lane = t & 63;
    int lrow = lane & 15, khalf = lane >> 4;
    f32x4 acc[4] = {};
    for (int kt = ksl * 256; kt < ksl * 256 + 256; kt += 128) {
#pragma unroll
        for (int i = 0; i < 4; ++i) {
            int rb = wid * 16 + i * 4;
            int row = rb + (lane >> 4);
            int gsrc = ((lane & 15) ^ (row & 15)) << 3;
            gload16(qb + (long)row * 8192 + kt + gsrc, &sQ[rb * 128]);
            gload16(kb + (long)row * 8192 + kt + gsrc, &sK[rb * 128]);
        }
        __syncthreads();
#pragma unroll
        for (int ks = 0; ks < 4; ++ks) {
            int gk = ks * 4 + khalf;
            h8_t kf = *(const h8_t*)&sK[swz128(wid * 16 + lrow, gk)];
#pragma unroll
            for (int mi = 0; mi < 4; ++mi) {
                h8_t qf = *(const h8_t*)&sQ[swz128(mi * 16 + lrow, gk)];
                acc[mi] = __builtin_amdgcn_mfma_f32_16x16x32_f16(qf, kf, acc[mi], 0, 0, 0);
            }
        }
        __syncthreads();
    }
    float* op = attn_part + (((long)b * 16 + ksl) * 8 + h) * 4096;
    int crow = (lane >> 4) * 4, ccol = lane & 15;
#pragma unroll
    for (int mi = 0; mi < 4; ++mi)
#pragma unroll
        for (int r = 0; r < 4; ++r)
            op[(mi * 16 + crow + r) * 64 + wid * 16 + ccol] = acc[mi][r];
}

// ---------------- fused 4x top-k masked softmax combine -> Wc (f32) ----------------
__global__ __launch_bounds__(256) void k_smcomb(const float* __restrict__ attn_part,
                                                const float* __restrict__ temp,
                                                const float* __restrict__ a1,
                                                const float* __restrict__ a2,
                                                const float* __restrict__ a3,
                                                const float* __restrict__ a4,
                                                float* __restrict__ Wc) {
    int t = threadIdx.x, wid = t >> 6, lane = t & 63;
    int b = blockIdx.z;
    int r = blockIdx.x * 4 + wid;   // (h, qrow) 0..511
    int h = r >> 6, qr = r & 63;
    float a = 0.f;
#pragma unroll
    for (int s = 0; s < 16; ++s)
        a += attn_part[(((long)b * 16 + s) * 8 + h) * 4096 + qr * 64 + lane];
    a *= temp[h];
    int cnt = 0;
#pragma unroll
    for (int j = 0; j < 64; ++j) {
        float aj = __shfl(a, j);
        cnt += (aj > a) ? 1 : 0;
    }
    float m = a;
#pragma unroll
    for (int o = 32; o; o >>= 1) m = fmaxf(m, __shfl_xor(m, o));
    float e = expf(a - m);
    const int kk[4] = {32, 42, 48, 51};
    float coef[4] = {a1[0], a2[0], a3[0], a4[0]};
    float out = 0.f;
#pragma unroll
    for (int i = 0; i < 4; ++i) {
        float ei = (cnt < kk[i]) ? e : 0.f;
        float d = ei;
#pragma unroll
        for (int o = 32; o; o >>= 1) d += __shfl_xor(d, o);
        out += coef[i] * ei / d;
    }
    Wc[((long)b * 8 + h) * 4096 + qr * 64 + lane] = out;
}

// ---------------- attT[n][c] = sum_d v[d][n]*Wc[c][d], f16 2-pass ----------------
// v (f16, slot first-half) transposed into LDS during staging (8-short-group XOR swizzle).
__global__ __launch_bounds__(256) void k_wv_f16(const float* __restrict__ Wc,
                                                const short* __restrict__ qkv_sh,
                                                short* __restrict__ attTs) {
    __shared__ short sVt[128 * 64];          // [n][d swizzled] f16 (16 KB)
    __shared__ short sWh[64 * 64], sWl[64 * 64];
    int nb = blockIdx.x, h = blockIdx.y, b = blockIdx.z;
    int n0 = nb * 128;
    const float* wp = Wc + ((long)b * 8 + h) * 4096;
    const short* vp = qkv_sh + ((long)b * C3 + 1024 + h * 64) * 8192L;  // slot stride 8192 sh
    int t = threadIdx.x, wid = t >> 6, lane = t & 63;
    int lrow = lane & 15, khalf = lane >> 4;
    // stage V: load v[d][n0+n8..+8] (d = lane, n8 = wave/p uniform), write transposed
#pragma unroll
    for (int p = 0; p < 4; ++p) {
        int d = lane;
        int n8 = (p * 4 + wid) * 8;
        short8 v8 = *(const short8*)&vp[(long)d * 8192 + n0 + n8];
#pragma unroll
        for (int j = 0; j < 8; ++j) {
            int n = n8 + j;
            sVt[n * 64 + (((d >> 3) ^ (n & 7)) << 3) + (d & 7)] = v8[j];
        }
    }
    // stage Wc hi/lo f16 planes
#pragma unroll
    for (int p = 0; p < 2; ++p) {
        int id = p * 256 + t, row = id >> 3, g = id & 7;
        f32x4 va = *(const f32x4*)&wp[row * 64 + g * 8];
        f32x4 vb = *(const f32x4*)&wp[row * 64 + g * 8 + 4];
        short8 hh, ll;
#pragma unroll
        for (int j = 0; j < 4; ++j) {
            short h0, l0, h1, l1;
            split_f16(va[j], h0, l0);
            split_f16(vb[j], h1, l1);
            hh[j] = h0;     ll[j] = l0;
            hh[4 + j] = h1; ll[4 + j] = l1;
        }
        int off = swz64(row, g);
        *(short8*)&sWh[off] = hh;
        *(short8*)&sWl[off] = ll;
    }
    __syncthreads();
    f32x4 acc[2][4] = {};
#pragma unroll
    for (int ks = 0; ks < 2; ++ks) {
        int gk = ks * 4 + khalf;
        h8_t vf[2], wh[4], wl[4];
#pragma unroll
        for (int i = 0; i < 2; ++i) {
            int n = wid * 32 + i * 16 + lrow;
            vf[i] = *(const h8_t*)&sVt[n * 64 + ((gk ^ (n & 7)) << 3)];
        }
#pragma unroll
        for (int i = 0; i < 4; ++i) {
            int rr = i * 16 + lrow;
            wh[i] = *(const h8_t*)&sWh[swz64(rr, gk)];
            wl[i] = *(const h8_t*)&sWl[swz64(rr, gk)];
        }
#pragma unroll
        for (int mi = 0; mi < 2; ++mi)
#pragma unroll
            for (int ni = 0; ni < 4; ++ni) {
                acc[mi][ni] = __builtin_amdgcn_mfma_f32_16x16x32_f16(
                    vf[mi], wh[ni], acc[mi][ni], 0, 0, 0);
                acc[mi][ni] = __builtin_amdgcn_mfma_f32_16x16x32_f16(
                    vf[mi], wl[ni], acc[mi][ni], 0, 0, 0);
            }
    }
    short* op = attTs + (long)b * ((long)C3 * 8192);
    int crow = (lane >> 4) * 4, ccol = lane & 15;
#pragma unroll
    for (int mi = 0; mi < 2; ++mi)
#pragma unroll
        for (int ni = 0; ni < 4; ++ni)
#pragma unroll
            for (int r = 0; r < 4; ++r) {
                long n = n0 + wid * 32 + mi * 16 + crow + r;
                int c = h * 64 + ni * 16 + ccol;
                op[n * CHN + c] = f2h_bits(acc[mi][ni][r]);
            }
}

extern "C" void kernel_launch(void* const* d_in, const int* in_sizes, int n_in,
                              void* d_out, int out_size, void* d_ws, size_t ws_size,
                              hipStream_t stream) {
    const float* x      = (const float*)d_in[0];
    const float* qkv_w  = (const float*)d_in[1];
    const float* dw_w   = (const float*)d_in[2];
    const float* proj_w = (const float*)d_in[3];
    const float* temp   = (const float*)d_in[4];
    const float* a1     = (const float*)d_in[5];
    const float* a2     = (const float*)d_in[6];
    const float* a3     = (const float*)d_in[7];
    const float* a4     = (const float*)d_in[8];
    float* out = (float*)d_out;

    // Adaptive grouping: single group of 8 batches needs 238,026,752 B;
    // fall back to the proven 2x4 grouping (120.6 MB) otherwise.
    const int GBv = (ws_size >= 238100000UL) ? 8 : 4;
    const int ngroups = 8 / GBv;

    char* ws = (char*)d_ws;
    // layout (runtime GBv):
    //   0                 qkvi [GBv][1536] x 16KB channel slots
    //                     (GEMM f16 out -> dwl2 in-place -> q-region reused as attT)
    //   qkviB             SHARED: xTs f16 [GBv][4096][512] then attn_part f32 [GBv][16][8][4096]
    //   qkviB+shB         Wc f32 [GBv][8][64][64]
    //   +WcB              wph (524,288 B)
    //   +524288           wqh (1,572,864 B)
    long qkviB = (long)GBv * C3 * 16384;
    long shB   = (long)GBv * 4194304;
    long WcB   = (long)GBv * 131072;
    short* qkvi      = (short*)(ws);
    short* xTs       = (short*)(ws + qkviB);
    float* attn_part = (float*)(ws + qkviB);
    float* Wc        = (float*)(ws + qkviB + shB);
    short* wph       = (short*)(ws + qkviB + shB + WcB);
    short* wqh       = (short*)(ws + qkviB + shB + WcB + 524288);

    k_w_hi2<<<1024, 256, 0, stream>>>(proj_w, wph, qkv_w, wqh);

    for (int g = 0; g < ngroups; ++g) {
        const float* xg = x + (long)g * GBv * CHN * HW;
        float* outg = out + (long)g * GBv * CHN * HW;
        // 1. x -> xTs f16 [n][c]
        k_transpose_xf16<<<dim3(64, 8, GBv), 256, 0, stream>>>(xg, xTs);
        // 2. qkv = Wqkv(f16 hi) * x, 1-pass, MT=128, f16 out into slot first-half
        k_gemm_f16<128, true><<<dim3(32, 12, GBv), 256, 0, stream>>>(
            wqh, xTs, qkvi, C3, HW, CHN,
            (long)HW * CHN, (long)C3 * 8192, 8192);
        // 3. depthwise 3x3 + q,k L2-norm: f16 in-place
        k_dwl2_rs<<<dim3(C3, GBv), 256, 0, stream>>>(qkvi, dw_w);
        // 4. attn partials (16 K-slices), 1-pass f16
        k_attn_gl<<<dim3(8, 16, GBv), 256, 0, stream>>>(qkvi, attn_part);
        // 5. fused top-k softmax combine (16-way partial sum)
        k_smcomb<<<dim3(128, 1, GBv), 256, 0, stream>>>(attn_part, temp, a1, a2, a3, a4, Wc);
        // 6. attT f16 = (Wc * v)^T, f16 2-pass, into dead q-region
        k_wv_f16<<<dim3(32, 8, GBv), 256, 0, stream>>>(Wc, qkvi, qkvi);
        // 7. out = Wproj(f16 hi) * att  (M=512, N=4096, K=512), 1-pass, f32 out
        k_gemm_f16<64, false><<<dim3(32, 8, GBv), 256, 0, stream>>>(
            wph, qkvi, outg, CHN, HW, CHN,
            (long)C3 * 8192, (long)CHN * HW, HW);
    }
}

// Round 18
// 230.834 us; speedup vs baseline: 1.3122x; 1.0013x over previous
//
#include <hip/hip_runtime.h>
#include <hip/hip_bf16.h>

#define CHN 512
#define HW  4096
#define C3  1536

typedef __hip_bfloat16 bf16;
typedef __attribute__((ext_vector_type(8))) short short8;
typedef __attribute__((ext_vector_type(4))) short short4v;
typedef __attribute__((ext_vector_type(4))) float f32x4;
typedef __attribute__((ext_vector_type(4))) int   int4v;
typedef _Float16 h8_t __attribute__((ext_vector_type(8)));

// f16 helpers: hi ~2^-12, hi+lo ~2^-22
__device__ inline short f2h_bits(float x) {
    _Float16 h = (_Float16)x;
    return __builtin_bit_cast(short, h);
}
__device__ inline float h2f_bits(short s) {
    return (float)__builtin_bit_cast(_Float16, s);
}
__device__ inline void split_f16(float x, short& hi, short& lo) {
    _Float16 h = (_Float16)x;
    _Float16 l = (_Float16)(x - (float)h);
    hi = __builtin_bit_cast(short, h);
    lo = __builtin_bit_cast(short, l);
}
// XOR-swizzled LDS index (short units): row-major [rows][64], 16B granules
__device__ inline int swz64(int row, int g) {
    return row * 64 + ((g ^ (row & 7)) << 3);
}
__device__ inline int swz128(int row, int g) {
    return row * 128 + ((g ^ (row & 15)) << 3);
}
// async global->LDS 16B: lane's data lands at lds_base + lane*16B
__device__ inline void gload16(const void* g, void* l) {
    __builtin_amdgcn_global_load_lds(
        (const __attribute__((address_space(1))) void*)g,
        (__attribute__((address_space(3))) void*)l, 16, 0, 0);
}

// ---------------- both weight tensors f32 -> f16 (hi), one launch ----------------
__global__ __launch_bounds__(256) void k_w_hi2(const float* __restrict__ wp_,
                                               short* __restrict__ wph,
                                               const float* __restrict__ wq_,
                                               short* __restrict__ wqh) {
    int i = blockIdx.x * 256 + threadIdx.x;
    const float* src;
    short* dst;
    int j;
    if (i < 65536) { src = wp_; dst = wph; j = i; }
    else           { src = wq_; dst = wqh; j = i - 65536; }
    f32x4 v = *(const f32x4*)&src[j * 4];
    short4v h;
#pragma unroll
    for (int k = 0; k < 4; ++k) h[k] = f2h_bits(v[k]);
    *(short4v*)&dst[j * 4] = h;
}

// ---------------- x [C][N] f32 -> xT [N][C] f16 ----------------
__global__ __launch_bounds__(256) void k_transpose_xf16(const float* __restrict__ in,
                                                        short* __restrict__ out) {
    __shared__ float tile[64][65];
    int b = blockIdx.z;
    int c0 = blockIdx.y * 64, n0 = blockIdx.x * 64;
    const float* ip = in + (long)b * ((long)CHN * HW);
    short* op = out + (long)b * ((long)HW * CHN);
    int t = threadIdx.x;
#pragma unroll
    for (int p = 0; p < 4; ++p) {
        int id = p * 256 + t;
        int r = id >> 4, c4 = (id & 15) * 4;
        f32x4 v = *(const f32x4*)&ip[(long)(c0 + r) * HW + n0 + c4];
#pragma unroll
        for (int j = 0; j < 4; ++j) tile[r][c4 + j] = v[j];
    }
    __syncthreads();
    int col = t & 63, rr = t >> 6;
#pragma unroll
    for (int p = 0; p < 16; ++p) {
        int r = p * 4 + rr;
        op[(long)(n0 + r) * CHN + c0 + col] = f2h_bits(tile[col][r]);
    }
}

// ---------------- GEMM: C[b] = A (MxK f16 hi) * B[b]^T (NxK f16), 1-pass ----------------
// (R13-proven geometry: MT=128, direct scalar stores)
template <int MT, bool OUT_F16>
__global__ __launch_bounds__(256) void k_gemm_f16(const short* __restrict__ Ah,
                                                  const short* __restrict__ B,
                                                  void* __restrict__ Cv,
                                                  int M, int N, int K,
                                                  long bB, long bC, long rstride) {
    __shared__ short sAh[MT * 64], sB[128 * 64];
    int b = blockIdx.z;
    int m0 = blockIdx.y * MT, n0 = blockIdx.x * 128;
    const short* Bp = B + (long)b * bB;
    int t = threadIdx.x, wid = t >> 6, lane = t & 63;
    int wr = (wid >> 1) * (MT / 2), wc = (wid & 1) * 64;
    int lrow = lane & 15, khalf = lane >> 4;
    int lrow8 = lane >> 3;                         // 0..7 within wave's 8 rows
    int gl = ((lane & 7) ^ lrow8) << 3;            // pre-swizzled source granule (shorts)
    constexpr int MR = MT / 32;                    // acc M-fragments per wave
    f32x4 acc[MR][4] = {};
    for (int kt = 0; kt < K; kt += 64) {
#pragma unroll
        for (int i = 0; i < MT / 32; ++i) {
            int rb = i * 32 + wid * 8;
            int row = rb + lrow8;
            gload16(&Ah[(long)(m0 + row) * K + kt + gl], &sAh[rb * 64]);
        }
#pragma unroll
        for (int i = 0; i < 4; ++i) {
            int rb = i * 32 + wid * 8;
            int row = rb + lrow8;
            gload16(&Bp[(long)(n0 + row) * K + kt + gl], &sB[rb * 64]);
        }
        __syncthreads();
#pragma unroll
        for (int ks = 0; ks < 2; ++ks) {
            int gk = ks * 4 + khalf;
            h8_t ah[MR], bh[4];
#pragma unroll
            for (int i = 0; i < MR; ++i)
                ah[i] = *(const h8_t*)&sAh[swz64(wr + i * 16 + lrow, gk)];
#pragma unroll
            for (int i = 0; i < 4; ++i)
                bh[i] = *(const h8_t*)&sB[swz64(wc + i * 16 + lrow, gk)];
#pragma unroll
            for (int mi = 0; mi < MR; ++mi)
#pragma unroll
                for (int ni = 0; ni < 4; ++ni)
                    acc[mi][ni] = __builtin_amdgcn_mfma_f32_16x16x32_f16(
                        ah[mi], bh[ni], acc[mi][ni], 0, 0, 0);
        }
        __syncthreads();
    }
    int crow = (lane >> 4) * 4, ccol = lane & 15;
#pragma unroll
    for (int mi = 0; mi < MR; ++mi)
#pragma unroll
        for (int ni = 0; ni < 4; ++ni)
#pragma unroll
            for (int r = 0; r < 4; ++r) {
                long row = m0 + wr + mi * 16 + crow + r;
                long col = n0 + wc + ni * 16 + ccol;
                float v = acc[mi][ni][r];
                if constexpr (OUT_F16)
                    ((short*)Cv)[(long)b * bC + row * rstride + col] = f2h_bits(v);
                else
                    ((float*)Cv)[(long)b * bC + row * rstride + col] = v;
            }
}

// ---------------- fused depthwise 3x3 + (q,k) L2-norm, register column-stencil ----------------
// Input: f16 in first 8KB of each 16KB channel slot. Output in-place: f16 first-half,
// q/k channels (ch<1024) scaled by 1/||.||.
__global__ __launch_bounds__(256) void k_dwl2_rs(short* __restrict__ qkv,
                                                 const float* __restrict__ w) {
    __shared__ float red[4];
    int ch = blockIdx.x, b = blockIdx.y;
    bool is_qk = ch < 1024;
    short* ps = qkv + ((long)b * C3 + ch) * 8192L;  // slot base (8192 shorts = 16KB)
    float w9[9];
#pragma unroll
    for (int i = 0; i < 9; ++i) w9[i] = w[ch * 9 + i];
    int t = threadIdx.x, wid = t >> 6, lane = t & 63;
    int y0 = wid * 16;
    float out[16];
#pragma unroll
    for (int j = 0; j < 16; ++j) out[j] = 0.f;
#pragma unroll
    for (int i = 0; i < 18; ++i) {
        int r = y0 - 1 + i;
        float v = (r >= 0 && r < 64) ? h2f_bits(ps[r * 64 + lane]) : 0.f;
        float vl = __shfl_up(v, 1);
        float vr = __shfl_down(v, 1);
        if (lane == 0) vl = 0.f;
        if (lane == 63) vr = 0.f;
        int j = i - 1;  // r - y0
        if (j + 1 >= 0 && j + 1 < 16) out[j + 1] += w9[0] * vl + w9[1] * v + w9[2] * vr;
        if (j >= 0 && j < 16)         out[j]     += w9[3] * vl + w9[4] * v + w9[5] * vr;
        if (j - 1 >= 0 && j - 1 < 16) out[j - 1] += w9[6] * vl + w9[7] * v + w9[8] * vr;
    }
    float sc = 1.f;
    if (is_qk) {
        float ss = 0.f;
#pragma unroll
        for (int j = 0; j < 16; ++j) ss += out[j] * out[j];
#pragma unroll
        for (int o = 32; o; o >>= 1) ss += __shfl_xor(ss, o);
        if (lane == 0) red[wid] = ss;
        __syncthreads();   // orders all loads before in-place stores
        float tot = red[0] + red[1] + red[2] + red[3];
        sc = 1.f / fmaxf(sqrtf(tot), 1e-12f);
    } else {
        __syncthreads();   // in-place safety: all loads before any store
    }
#pragma unroll
    for (int j = 0; j < 16; ++j)
        ps[(y0 + j) * 64 + lane] = f2h_bits(out[j] * sc);
}

// ---------------- attn partials: per (h, kslice, b): q(64xK)*k(64xK)^T, 1-pass f16 ----------------
// 16 K-slices of 256; q/k staged via global_load_lds (pre-swizzled source).
__global__ __launch_bounds__(256) void k_attn_gl(const short* __restrict__ qkv_sh,
                                                 float* __restrict__ attn_part) {
    __shared__ short sQ[64 * 128], sK[64 * 128];
    int h = blockIdx.x, ksl = blockIdx.y, b = blockIdx.z;
    const short* qb = qkv_sh + ((long)b * C3 + h * 64) * 8192L;   // f16 plane, slot stride
    const short* kb = qb + (long)512 * 8192;
    int t = threadIdx.x, wid = t >> 6, lane = t & 63;
    int lrow = lane & 15, khalf = lane >> 4;
    f32x4 acc[4] = {};
    for (int kt = ksl * 256; kt < ksl * 256 + 256; kt += 128) {
#pragma unroll
        for (int i = 0; i < 4; ++i) {
            int rb = wid * 16 + i * 4;
            int row = rb + (lane >> 4);
            int gsrc = ((lane & 15) ^ (row & 15)) << 3;
            gload16(qb + (long)row * 8192 + kt + gsrc, &sQ[rb * 128]);
            gload16(kb + (long)row * 8192 + kt + gsrc, &sK[rb * 128]);
        }
        __syncthreads();
#pragma unroll
        for (int ks = 0; ks < 4; ++ks) {
            int gk = ks * 4 + khalf;
            h8_t kf = *(const h8_t*)&sK[swz128(wid * 16 + lrow, gk)];
#pragma unroll
            for (int mi = 0; mi < 4; ++mi) {
                h8_t qf = *(const h8_t*)&sQ[swz128(mi * 16 + lrow, gk)];
                acc[mi] = __builtin_amdgcn_mfma_f32_16x16x32_f16(qf, kf, acc[mi], 0, 0, 0);
            }
        }
        __syncthreads();
    }
    float* op = attn_part + (((long)b * 16 + ksl) * 8 + h) * 4096;
    int crow = (lane >> 4) * 4, ccol = lane & 15;
#pragma unroll
    for (int mi = 0; mi < 4; ++mi)
#pragma unroll
        for (int r = 0; r < 4; ++r)
            op[(mi * 16 + crow + r) * 64 + wid * 16 + ccol] = acc[mi][r];
}

// ---------------- fused 4x top-k masked softmax combine -> Wc (f32) ----------------
__global__ __launch_bounds__(256) void k_smcomb(const float* __restrict__ attn_part,
                                                const float* __restrict__ temp,
                                                const float* __restrict__ a1,
                                                const float* __restrict__ a2,
                                                const float* __restrict__ a3,
                                                const float* __restrict__ a4,
                                                float* __restrict__ Wc) {
    int t = threadIdx.x, wid = t >> 6, lane = t & 63;
    int b = blockIdx.z;
    int r = blockIdx.x * 4 + wid;   // (h, qrow) 0..511
    int h = r >> 6, qr = r & 63;
    float a = 0.f;
#pragma unroll
    for (int s = 0; s < 16; ++s)
        a += attn_part[(((long)b * 16 + s) * 8 + h) * 4096 + qr * 64 + lane];
    a *= temp[h];
    int cnt = 0;
#pragma unroll
    for (int j = 0; j < 64; ++j) {
        float aj = __shfl(a, j);
        cnt += (aj > a) ? 1 : 0;
    }
    float m = a;
#pragma unroll
    for (int o = 32; o; o >>= 1) m = fmaxf(m, __shfl_xor(m, o));
    float e = expf(a - m);
    const int kk[4] = {32, 42, 48, 51};
    float coef[4] = {a1[0], a2[0], a3[0], a4[0]};
    float out = 0.f;
#pragma unroll
    for (int i = 0; i < 4; ++i) {
        float ei = (cnt < kk[i]) ? e : 0.f;
        float d = ei;
#pragma unroll
        for (int o = 32; o; o >>= 1) d += __shfl_xor(d, o);
        out += coef[i] * ei / d;
    }
    Wc[((long)b * 8 + h) * 4096 + qr * 64 + lane] = out;
}

// ---------------- attT[n][c] = sum_d v[d][n]*Wc[c][d], f16 2-pass ----------------
// v (f16, slot first-half) transposed into LDS during staging (8-short-group XOR swizzle).
__global__ __launch_bounds__(256) void k_wv_f16(const float* __restrict__ Wc,
                                                const short* __restrict__ qkv_sh,
                                                short* __restrict__ attTs) {
    __shared__ short sVt[128 * 64];          // [n][d swizzled] f16 (16 KB)
    __shared__ short sWh[64 * 64], sWl[64 * 64];
    int nb = blockIdx.x, h = blockIdx.y, b = blockIdx.z;
    int n0 = nb * 128;
    const float* wp = Wc + ((long)b * 8 + h) * 4096;
    const short* vp = qkv_sh + ((long)b * C3 + 1024 + h * 64) * 8192L;  // slot stride 8192 sh
    int t = threadIdx.x, wid = t >> 6, lane = t & 63;
    int lrow = lane & 15, khalf = lane >> 4;
    // stage V: load v[d][n0+n8..+8] (d = lane, n8 = wave/p uniform), write transposed
#pragma unroll
    for (int p = 0; p < 4; ++p) {
        int d = lane;
        int n8 = (p * 4 + wid) * 8;
        short8 v8 = *(const short8*)&vp[(long)d * 8192 + n0 + n8];
#pragma unroll
        for (int j = 0; j < 8; ++j) {
            int n = n8 + j;
            sVt[n * 64 + (((d >> 3) ^ (n & 7)) << 3) + (d & 7)] = v8[j];
        }
    }
    // stage Wc hi/lo f16 planes
#pragma unroll
    for (int p = 0; p < 2; ++p) {
        int id = p * 256 + t, row = id >> 3, g = id & 7;
        f32x4 va = *(const f32x4*)&wp[row * 64 + g * 8];
        f32x4 vb = *(const f32x4*)&wp[row * 64 + g * 8 + 4];
        short8 hh, ll;
#pragma unroll
        for (int j = 0; j < 4; ++j) {
            short h0, l0, h1, l1;
            split_f16(va[j], h0, l0);
            split_f16(vb[j], h1, l1);
            hh[j] = h0;     ll[j] = l0;
            hh[4 + j] = h1; ll[4 + j] = l1;
        }
        int off = swz64(row, g);
        *(short8*)&sWh[off] = hh;
        *(short8*)&sWl[off] = ll;
    }
    __syncthreads();
    f32x4 acc[2][4] = {};
#pragma unroll
    for (int ks = 0; ks < 2; ++ks) {
        int gk = ks * 4 + khalf;
        h8_t vf[2], wh[4], wl[4];
#pragma unroll
        for (int i = 0; i < 2; ++i) {
            int n = wid * 32 + i * 16 + lrow;
            vf[i] = *(const h8_t*)&sVt[n * 64 + ((gk ^ (n & 7)) << 3)];
        }
#pragma unroll
        for (int i = 0; i < 4; ++i) {
            int rr = i * 16 + lrow;
            wh[i] = *(const h8_t*)&sWh[swz64(rr, gk)];
            wl[i] = *(const h8_t*)&sWl[swz64(rr, gk)];
        }
#pragma unroll
        for (int mi = 0; mi < 2; ++mi)
#pragma unroll
            for (int ni = 0; ni < 4; ++ni) {
                acc[mi][ni] = __builtin_amdgcn_mfma_f32_16x16x32_f16(
                    vf[mi], wh[ni], acc[mi][ni], 0, 0, 0);
                acc[mi][ni] = __builtin_amdgcn_mfma_f32_16x16x32_f16(
                    vf[mi], wl[ni], acc[mi][ni], 0, 0, 0);
            }
    }
    short* op = attTs + (long)b * ((long)C3 * 8192);
    int crow = (lane >> 4) * 4, ccol = lane & 15;
#pragma unroll
    for (int mi = 0; mi < 2; ++mi)
#pragma unroll
        for (int ni = 0; ni < 4; ++ni)
#pragma unroll
            for (int r = 0; r < 4; ++r) {
                long n = n0 + wid * 32 + mi * 16 + crow + r;
                int c = h * 64 + ni * 16 + ccol;
                op[n * CHN + c] = f2h_bits(acc[mi][ni][r]);
            }
}

extern "C" void kernel_launch(void* const* d_in, const int* in_sizes, int n_in,
                              void* d_out, int out_size, void* d_ws, size_t ws_size,
                              hipStream_t stream) {
    const float* x      = (const float*)d_in[0];
    const float* qkv_w  = (const float*)d_in[1];
    const float* dw_w   = (const float*)d_in[2];
    const float* proj_w = (const float*)d_in[3];
    const float* temp   = (const float*)d_in[4];
    const float* a1     = (const float*)d_in[5];
    const float* a2     = (const float*)d_in[6];
    const float* a3     = (const float*)d_in[7];
    const float* a4     = (const float*)d_in[8];
    float* out = (float*)d_out;

    // Adaptive grouping: single group of 8 batches needs 238,026,752 B;
    // fall back to the proven 2x4 grouping (120.6 MB) otherwise.
    const int GBv = (ws_size >= 238100000UL) ? 8 : 4;
    const int ngroups = 8 / GBv;

    char* ws = (char*)d_ws;
    // layout (runtime GBv):
    //   0                 qkvi [GBv][1536] x 16KB channel slots
    //                     (GEMM f16 out -> dwl2 in-place -> q-region reused as attT)
    //   qkviB             SHARED: xTs f16 [GBv][4096][512] then attn_part f32 [GBv][16][8][4096]
    //   qkviB+shB         Wc f32 [GBv][8][64][64]
    //   +WcB              wph (524,288 B)
    //   +524288           wqh (1,572,864 B)
    long qkviB = (long)GBv * C3 * 16384;
    long shB   = (long)GBv * 4194304;
    long WcB   = (long)GBv * 131072;
    short* qkvi      = (short*)(ws);
    short* xTs       = (short*)(ws + qkviB);
    float* attn_part = (float*)(ws + qkviB);
    float* Wc        = (float*)(ws + qkviB + shB);
    short* wph       = (short*)(ws + qkviB + shB + WcB);
    short* wqh       = (short*)(ws + qkviB + shB + WcB + 524288);

    k_w_hi2<<<1024, 256, 0, stream>>>(proj_w, wph, qkv_w, wqh);

    for (int g = 0; g < ngroups; ++g) {
        const float* xg = x + (long)g * GBv * CHN * HW;
        float* outg = out + (long)g * GBv * CHN * HW;
        // 1. x -> xTs f16 [n][c]
        k_transpose_xf16<<<dim3(64, 8, GBv), 256, 0, stream>>>(xg, xTs);
        // 2. qkv = Wqkv(f16 hi) * x, 1-pass, MT=128, f16 out into slot first-half
        k_gemm_f16<128, true><<<dim3(32, 12, GBv), 256, 0, stream>>>(
            wqh, xTs, qkvi, C3, HW, CHN,
            (long)HW * CHN, (long)C3 * 8192, 8192);
        // 3. depthwise 3x3 + q,k L2-norm: f16 in-place
        k_dwl2_rs<<<dim3(C3, GBv), 256, 0, stream>>>(qkvi, dw_w);
        // 4. attn partials (16 K-slices), 1-pass f16
        k_attn_gl<<<dim3(8, 16, GBv), 256, 0, stream>>>(qkvi, attn_part);
        // 5. fused top-k softmax combine (16-way partial sum)
        k_smcomb<<<dim3(128, 1, GBv), 256, 0, stream>>>(attn_part, temp, a1, a2, a3, a4, Wc);
        // 6. attT f16 = (Wc * v)^T, f16 2-pass, into dead q-region
        k_wv_f16<<<dim3(32, 8, GBv), 256, 0, stream>>>(Wc, qkvi, qkvi);
        // 7. out = Wproj(f16 hi) * att  (M=512, N=4096, K=512), 1-pass, MT=128, f32 out
        k_gemm_f16<128, false><<<dim3(32, 4, GBv), 256, 0, stream>>>(
            wph, qkvi, outg, CHN, HW, CHN,
            (long)C3 * 8192, (long)CHN * HW, HW);
    }
}

// Round 19
// 228.846 us; speedup vs baseline: 1.3236x; 1.0087x over previous
//
#include <hip/hip_runtime.h>
#include <hip/hip_bf16.h>

#define CHN 512
#define HW  4096
#define C3  1536

typedef __hip_bfloat16 bf16;
typedef __attribute__((ext_vector_type(8))) short short8;
typedef __attribute__((ext_vector_type(4))) short short4v;
typedef __attribute__((ext_vector_type(4))) float f32x4;
typedef __attribute__((ext_vector_type(4))) int   int4v;
typedef _Float16 h8_t __attribute__((ext_vector_type(8)));

// f16 helpers: hi ~2^-12, hi+lo ~2^-22
__device__ inline short f2h_bits(float x) {
    _Float16 h = (_Float16)x;
    return __builtin_bit_cast(short, h);
}
__device__ inline float h2f_bits(short s) {
    return (float)__builtin_bit_cast(_Float16, s);
}
__device__ inline void split_f16(float x, short& hi, short& lo) {
    _Float16 h = (_Float16)x;
    _Float16 l = (_Float16)(x - (float)h);
    hi = __builtin_bit_cast(short, h);
    lo = __builtin_bit_cast(short, l);
}
// XOR-swizzled LDS index (short units): row-major [rows][64], 16B granules
__device__ inline int swz64(int row, int g) {
    return row * 64 + ((g ^ (row & 7)) << 3);
}
__device__ inline int swz128(int row, int g) {
    return row * 128 + ((g ^ (row & 15)) << 3);
}
// async global->LDS 16B: lane's data lands at lds_base + lane*16B
__device__ inline void gload16(const void* g, void* l) {
    __builtin_amdgcn_global_load_lds(
        (const __attribute__((address_space(1))) void*)g,
        (__attribute__((address_space(3))) void*)l, 16, 0, 0);
}

// ---------------- both weight tensors f32 -> f16 (hi), one launch ----------------
__global__ __launch_bounds__(256) void k_w_hi2(const float* __restrict__ wp_,
                                               short* __restrict__ wph,
                                               const float* __restrict__ wq_,
                                               short* __restrict__ wqh) {
    int i = blockIdx.x * 256 + threadIdx.x;
    const float* src;
    short* dst;
    int j;
    if (i < 65536) { src = wp_; dst = wph; j = i; }
    else           { src = wq_; dst = wqh; j = i - 65536; }
    f32x4 v = *(const f32x4*)&src[j * 4];
    short4v h;
#pragma unroll
    for (int k = 0; k < 4; ++k) h[k] = f2h_bits(v[k]);
    *(short4v*)&dst[j * 4] = h;
}

// ---------------- x [C][N] f32 -> xT [N][C] f16 ----------------
__global__ __launch_bounds__(256) void k_transpose_xf16(const float* __restrict__ in,
                                                        short* __restrict__ out) {
    __shared__ float tile[64][65];
    int b = blockIdx.z;
    int c0 = blockIdx.y * 64, n0 = blockIdx.x * 64;
    const float* ip = in + (long)b * ((long)CHN * HW);
    short* op = out + (long)b * ((long)HW * CHN);
    int t = threadIdx.x;
#pragma unroll
    for (int p = 0; p < 4; ++p) {
        int id = p * 256 + t;
        int r = id >> 4, c4 = (id & 15) * 4;
        f32x4 v = *(const f32x4*)&ip[(long)(c0 + r) * HW + n0 + c4];
#pragma unroll
        for (int j = 0; j < 4; ++j) tile[r][c4 + j] = v[j];
    }
    __syncthreads();
    int col = t & 63, rr = t >> 6;
#pragma unroll
    for (int p = 0; p < 16; ++p) {
        int r = p * 4 + rr;
        op[(long)(n0 + r) * CHN + c0 + col] = f2h_bits(tile[col][r]);
    }
}

// ---------------- GEMM: C[b] = A (MxK f16 hi) * B[b]^T (NxK f16), 1-pass ----------------
// R13 geometry; staging/epilogue pointers strength-reduced.
template <int MT, bool OUT_F16>
__global__ __launch_bounds__(256) void k_gemm_f16(const short* __restrict__ Ah,
                                                  const short* __restrict__ B,
                                                  void* __restrict__ Cv,
                                                  int M, int N, int K,
                                                  long bB, long bC, long rstride) {
    __shared__ short sAh[MT * 64], sB[128 * 64];
    int b = blockIdx.z;
    int m0 = blockIdx.y * MT, n0 = blockIdx.x * 128;
    const short* Bp = B + (long)b * bB;
    int t = threadIdx.x, wid = t >> 6, lane = t & 63;
    int wr = (wid >> 1) * (MT / 2), wc = (wid & 1) * 64;
    int lrow = lane & 15, khalf = lane >> 4;
    int lrow8 = lane >> 3;                         // 0..7 within wave's 8 rows
    int gl = ((lane & 7) ^ lrow8) << 3;            // pre-swizzled source granule (shorts)
    constexpr int MR = MT / 32;                    // acc M-fragments per wave
    // hoisted staging pointers (constant-indexed arrays -> registers)
    const short* pa[MR];
#pragma unroll
    for (int i = 0; i < MR; ++i)
        pa[i] = &Ah[(long)(m0 + i * 32 + wid * 8 + lrow8) * K + gl];
    const short* pb[4];
#pragma unroll
    for (int i = 0; i < 4; ++i)
        pb[i] = &Bp[(long)(n0 + i * 32 + wid * 8 + lrow8) * K + gl];
    f32x4 acc[MR][4] = {};
    for (int kt = 0; kt < K; kt += 64) {
#pragma unroll
        for (int i = 0; i < MR; ++i) {
            gload16(pa[i], &sAh[(i * 32 + wid * 8) * 64]);
            pa[i] += 64;
        }
#pragma unroll
        for (int i = 0; i < 4; ++i) {
            gload16(pb[i], &sB[(i * 32 + wid * 8) * 64]);
            pb[i] += 64;
        }
        __syncthreads();
#pragma unroll
        for (int ks = 0; ks < 2; ++ks) {
            int gk = ks * 4 + khalf;
            h8_t ah[MR], bh[4];
#pragma unroll
            for (int i = 0; i < MR; ++i)
                ah[i] = *(const h8_t*)&sAh[swz64(wr + i * 16 + lrow, gk)];
#pragma unroll
            for (int i = 0; i < 4; ++i)
                bh[i] = *(const h8_t*)&sB[swz64(wc + i * 16 + lrow, gk)];
#pragma unroll
            for (int mi = 0; mi < MR; ++mi)
#pragma unroll
                for (int ni = 0; ni < 4; ++ni)
                    acc[mi][ni] = __builtin_amdgcn_mfma_f32_16x16x32_f16(
                        ah[mi], bh[ni], acc[mi][ni], 0, 0, 0);
        }
        __syncthreads();
    }
    int crow = (lane >> 4) * 4, ccol = lane & 15;
#pragma unroll
    for (int mi = 0; mi < MR; ++mi)
#pragma unroll
        for (int ni = 0; ni < 4; ++ni) {
            long row0 = m0 + wr + mi * 16 + crow;
            long col  = n0 + wc + ni * 16 + ccol;
            if constexpr (OUT_F16) {
                short* cp = (short*)Cv + (long)b * bC + row0 * rstride + col;
#pragma unroll
                for (int r = 0; r < 4; ++r) {
                    *cp = f2h_bits(acc[mi][ni][r]);
                    cp += rstride;
                }
            } else {
                float* cp = (float*)Cv + (long)b * bC + row0 * rstride + col;
#pragma unroll
                for (int r = 0; r < 4; ++r) {
                    *cp = acc[mi][ni][r];
                    cp += rstride;
                }
            }
        }
}

// ---------------- fused depthwise 3x3 + (q,k) L2-norm, register column-stencil ----------------
// Input: f16 in first 8KB of each 16KB channel slot. Output in-place: f16 first-half,
// q/k channels (ch<1024) scaled by 1/||.||.
__global__ __launch_bounds__(256) void k_dwl2_rs(short* __restrict__ qkv,
                                                 const float* __restrict__ w) {
    __shared__ float red[4];
    int ch = blockIdx.x, b = blockIdx.y;
    bool is_qk = ch < 1024;
    short* ps = qkv + ((long)b * C3 + ch) * 8192L;  // slot base (8192 shorts = 16KB)
    float w9[9];
#pragma unroll
    for (int i = 0; i < 9; ++i) w9[i] = w[ch * 9 + i];
    int t = threadIdx.x, wid = t >> 6, lane = t & 63;
    int y0 = wid * 16;
    float out[16];
#pragma unroll
    for (int j = 0; j < 16; ++j) out[j] = 0.f;
#pragma unroll
    for (int i = 0; i < 18; ++i) {
        int r = y0 - 1 + i;
        float v = (r >= 0 && r < 64) ? h2f_bits(ps[r * 64 + lane]) : 0.f;
        float vl = __shfl_up(v, 1);
        float vr = __shfl_down(v, 1);
        if (lane == 0) vl = 0.f;
        if (lane == 63) vr = 0.f;
        int j = i - 1;  // r - y0
        if (j + 1 >= 0 && j + 1 < 16) out[j + 1] += w9[0] * vl + w9[1] * v + w9[2] * vr;
        if (j >= 0 && j < 16)         out[j]     += w9[3] * vl + w9[4] * v + w9[5] * vr;
        if (j - 1 >= 0 && j - 1 < 16) out[j - 1] += w9[6] * vl + w9[7] * v + w9[8] * vr;
    }
    float sc = 1.f;
    if (is_qk) {
        float ss = 0.f;
#pragma unroll
        for (int j = 0; j < 16; ++j) ss += out[j] * out[j];
#pragma unroll
        for (int o = 32; o; o >>= 1) ss += __shfl_xor(ss, o);
        if (lane == 0) red[wid] = ss;
        __syncthreads();   // orders all loads before in-place stores
        float tot = red[0] + red[1] + red[2] + red[3];
        sc = 1.f / fmaxf(sqrtf(tot), 1e-12f);
    } else {
        __syncthreads();   // in-place safety: all loads before any store
    }
#pragma unroll
    for (int j = 0; j < 16; ++j)
        ps[(y0 + j) * 64 + lane] = f2h_bits(out[j] * sc);
}

// ---------------- attn partials: per (h, kslice, b): q(64xK)*k(64xK)^T, 1-pass f16 ----------------
// 16 K-slices of 256; q/k staged via global_load_lds (pre-swizzled source, hoisted ptrs).
__global__ __launch_bounds__(256) void k_attn_gl(const short* __restrict__ qkv_sh,
                                                 float* __restrict__ attn_part) {
    __shared__ short sQ[64 * 128], sK[64 * 128];
    int h = blockIdx.x, ksl = blockIdx.y, b = blockIdx.z;
    const short* qb = qkv_sh + ((long)b * C3 + h * 64) * 8192L;   // f16 plane, slot stride
    const short* kb = qb + (long)512 * 8192;
    int t = threadIdx.x, wid = t >> 6, lane = t & 63;
    int lrow = lane & 15, khalf = lane >> 4;
    // hoisted staging pointers
    const short* pq[4];
    const short* pk[4];
#pragma unroll
    for (int i = 0; i < 4; ++i) {
        int rb = wid * 16 + i * 4;
        int row = rb + (lane >> 4);
        int gsrc = ((lane & 15) ^ (row & 15)) << 3;
        pq[i] = qb + (long)row * 8192 + ksl * 256 + gsrc;
        pk[i] = kb + (long)row * 8192 + ksl * 256 + gsrc;
    }
    f32x4 acc[4] = {};
#pragma unroll
    for (int kti = 0; kti < 2; ++kti) {
#pragma unroll
        for (int i = 0; i < 4; ++i) {
            int rb = wid * 16 + i * 4;
            gload16(pq[i], &sQ[rb * 128]);
            gload16(pk[i], &sK[rb * 128]);
            pq[i] += 128;
            pk[i] += 128;
        }
        __syncthreads();
#pragma unroll
        for (int ks = 0; ks < 4; ++ks) {
            int gk = ks * 4 + khalf;
            h8_t kf = *(const h8_t*)&sK[swz128(wid * 16 + lrow, gk)];
#pragma unroll
            for (int mi = 0; mi < 4; ++mi) {
                h8_t qf = *(const h8_t*)&sQ[swz128(mi * 16 + lrow, gk)];
                acc[mi] = __builtin_amdgcn_mfma_f32_16x16x32_f16(qf, kf, acc[mi], 0, 0, 0);
            }
        }
        __syncthreads();
    }
    float* op = attn_part + (((long)b * 16 + ksl) * 8 + h) * 4096;
    int crow = (lane >> 4) * 4, ccol = lane & 15;
#pragma unroll
    for (int mi = 0; mi < 4; ++mi)
#pragma unroll
        for (int r = 0; r < 4; ++r)
            op[(mi * 16 + crow + r) * 64 + wid * 16 + ccol] = acc[mi][r];
}

// ---------------- fused 4x top-k masked softmax combine -> Wc (f32) ----------------
__global__ __launch_bounds__(256) void k_smcomb(const float* __restrict__ attn_part,
                                                const float* __restrict__ temp,
                                                const float* __restrict__ a1,
                                                const float* __restrict__ a2,
                                                const float* __restrict__ a3,
                                                const float* __restrict__ a4,
                                                float* __restrict__ Wc) {
    int t = threadIdx.x, wid = t >> 6, lane = t & 63;
    int b = blockIdx.z;
    int r = blockIdx.x * 4 + wid;   // (h, qrow) 0..511
    int h = r >> 6, qr = r & 63;
    float a = 0.f;
#pragma unroll
    for (int s = 0; s < 16; ++s)
        a += attn_part[(((long)b * 16 + s) * 8 + h) * 4096 + qr * 64 + lane];
    a *= temp[h];
    int cnt = 0;
#pragma unroll
    for (int j = 0; j < 64; ++j) {
        float aj = __shfl(a, j);
        cnt += (aj > a) ? 1 : 0;
    }
    float m = a;
#pragma unroll
    for (int o = 32; o; o >>= 1) m = fmaxf(m, __shfl_xor(m, o));
    float e = expf(a - m);
    const int kk[4] = {32, 42, 48, 51};
    float coef[4] = {a1[0], a2[0], a3[0], a4[0]};
    float out = 0.f;
#pragma unroll
    for (int i = 0; i < 4; ++i) {
        float ei = (cnt < kk[i]) ? e : 0.f;
        float d = ei;
#pragma unroll
        for (int o = 32; o; o >>= 1) d += __shfl_xor(d, o);
        out += coef[i] * ei / d;
    }
    Wc[((long)b * 8 + h) * 4096 + qr * 64 + lane] = out;
}

// ---------------- attT[n][c] = sum_d v[d][n]*Wc[c][d], f16 2-pass ----------------
// v (f16, slot first-half) transposed into LDS during staging (8-short-group XOR swizzle).
__global__ __launch_bounds__(256) void k_wv_f16(const float* __restrict__ Wc,
                                                const short* __restrict__ qkv_sh,
                                                short* __restrict__ attTs) {
    __shared__ short sVt[128 * 64];          // [n][d swizzled] f16 (16 KB)
    __shared__ short sWh[64 * 64], sWl[64 * 64];
    int nb = blockIdx.x, h = blockIdx.y, b = blockIdx.z;
    int n0 = nb * 128;
    const float* wp = Wc + ((long)b * 8 + h) * 4096;
    const short* vp = qkv_sh + ((long)b * C3 + 1024 + h * 64) * 8192L;  // slot stride 8192 sh
    int t = threadIdx.x, wid = t >> 6, lane = t & 63;
    int lrow = lane & 15, khalf = lane >> 4;
    // stage V: load v[d][n0+n8..+8] (d = lane, n8 = wave/p uniform), write transposed
#pragma unroll
    for (int p = 0; p < 4; ++p) {
        int d = lane;
        int n8 = (p * 4 + wid) * 8;
        short8 v8 = *(const short8*)&vp[(long)d * 8192 + n0 + n8];
#pragma unroll
        for (int j = 0; j < 8; ++j) {
            int n = n8 + j;
            sVt[n * 64 + (((d >> 3) ^ (n & 7)) << 3) + (d & 7)] = v8[j];
        }
    }
    // stage Wc hi/lo f16 planes
#pragma unroll
    for (int p = 0; p < 2; ++p) {
        int id = p * 256 + t, row = id >> 3, g = id & 7;
        f32x4 va = *(const f32x4*)&wp[row * 64 + g * 8];
        f32x4 vb = *(const f32x4*)&wp[row * 64 + g * 8 + 4];
        short8 hh, ll;
#pragma unroll
        for (int j = 0; j < 4; ++j) {
            short h0, l0, h1, l1;
            split_f16(va[j], h0, l0);
            split_f16(vb[j], h1, l1);
            hh[j] = h0;     ll[j] = l0;
            hh[4 + j] = h1; ll[4 + j] = l1;
        }
        int off = swz64(row, g);
        *(short8*)&sWh[off] = hh;
        *(short8*)&sWl[off] = ll;
    }
    __syncthreads();
    f32x4 acc[2][4] = {};
#pragma unroll
    for (int ks = 0; ks < 2; ++ks) {
        int gk = ks * 4 + khalf;
        h8_t vf[2], wh[4], wl[4];
#pragma unroll
        for (int i = 0; i < 2; ++i) {
            int n = wid * 32 + i * 16 + lrow;
            vf[i] = *(const h8_t*)&sVt[n * 64 + ((gk ^ (n & 7)) << 3)];
        }
#pragma unroll
        for (int i = 0; i < 4; ++i) {
            int rr = i * 16 + lrow;
            wh[i] = *(const h8_t*)&sWh[swz64(rr, gk)];
            wl[i] = *(const h8_t*)&sWl[swz64(rr, gk)];
        }
#pragma unroll
        for (int mi = 0; mi < 2; ++mi)
#pragma unroll
            for (int ni = 0; ni < 4; ++ni) {
                acc[mi][ni] = __builtin_amdgcn_mfma_f32_16x16x32_f16(
                    vf[mi], wh[ni], acc[mi][ni], 0, 0, 0);
                acc[mi][ni] = __builtin_amdgcn_mfma_f32_16x16x32_f16(
                    vf[mi], wl[ni], acc[mi][ni], 0, 0, 0);
            }
    }
    short* op = attTs + (long)b * ((long)C3 * 8192);
    int crow = (lane >> 4) * 4, ccol = lane & 15;
#pragma unroll
    for (int mi = 0; mi < 2; ++mi)
#pragma unroll
        for (int ni = 0; ni < 4; ++ni)
#pragma unroll
            for (int r = 0; r < 4; ++r) {
                long n = n0 + wid * 32 + mi * 16 + crow + r;
                int c = h * 64 + ni * 16 + ccol;
                op[n * CHN + c] = f2h_bits(acc[mi][ni][r]);
            }
}

extern "C" void kernel_launch(void* const* d_in, const int* in_sizes, int n_in,
                              void* d_out, int out_size, void* d_ws, size_t ws_size,
                              hipStream_t stream) {
    const float* x      = (const float*)d_in[0];
    const float* qkv_w  = (const float*)d_in[1];
    const float* dw_w   = (const float*)d_in[2];
    const float* proj_w = (const float*)d_in[3];
    const float* temp   = (const float*)d_in[4];
    const float* a1     = (const float*)d_in[5];
    const float* a2     = (const float*)d_in[6];
    const float* a3     = (const float*)d_in[7];
    const float* a4     = (const float*)d_in[8];
    float* out = (float*)d_out;

    // Adaptive grouping: single group of 8 batches needs 238,026,752 B;
    // fall back to the proven 2x4 grouping (120.6 MB) otherwise.
    const int GBv = (ws_size >= 238100000UL) ? 8 : 4;
    const int ngroups = 8 / GBv;

    char* ws = (char*)d_ws;
    long qkviB = (long)GBv * C3 * 16384;
    long shB   = (long)GBv * 4194304;
    long WcB   = (long)GBv * 131072;
    short* qkvi      = (short*)(ws);
    short* xTs       = (short*)(ws + qkviB);
    float* attn_part = (float*)(ws + qkviB);
    float* Wc        = (float*)(ws + qkviB + shB);
    short* wph       = (short*)(ws + qkviB + shB + WcB);
    short* wqh       = (short*)(ws + qkviB + shB + WcB + 524288);

    k_w_hi2<<<1024, 256, 0, stream>>>(proj_w, wph, qkv_w, wqh);

    for (int g = 0; g < ngroups; ++g) {
        const float* xg = x + (long)g * GBv * CHN * HW;
        float* outg = out + (long)g * GBv * CHN * HW;
        // 1. x -> xTs f16 [n][c]
        k_transpose_xf16<<<dim3(64, 8, GBv), 256, 0, stream>>>(xg, xTs);
        // 2. qkv = Wqkv(f16 hi) * x, 1-pass, MT=128, f16 out into slot first-half
        k_gemm_f16<128, true><<<dim3(32, 12, GBv), 256, 0, stream>>>(
            wqh, xTs, qkvi, C3, HW, CHN,
            (long)HW * CHN, (long)C3 * 8192, 8192);
        // 3. depthwise 3x3 + q,k L2-norm: f16 in-place
        k_dwl2_rs<<<dim3(C3, GBv), 256, 0, stream>>>(qkvi, dw_w);
        // 4. attn partials (16 K-slices), 1-pass f16
        k_attn_gl<<<dim3(8, 16, GBv), 256, 0, stream>>>(qkvi, attn_part);
        // 5. fused top-k softmax combine (16-way partial sum)
        k_smcomb<<<dim3(128, 1, GBv), 256, 0, stream>>>(attn_part, temp, a1, a2, a3, a4, Wc);
        // 6. attT f16 = (Wc * v)^T, f16 2-pass, into dead q-region
        k_wv_f16<<<dim3(32, 8, GBv), 256, 0, stream>>>(Wc, qkvi, qkvi);
        // 7. out = Wproj(f16 hi) * att  (M=512, N=4096, K=512), 1-pass, MT=128, f32 out
        k_gemm_f16<128, false><<<dim3(32, 4, GBv), 256, 0, stream>>>(
            wph, qkvi, outg, CHN, HW, CHN,
            (long)C3 * 8192, (long)CHN * HW, HW);
    }
}